// Round 9
// baseline (727.001 us; speedup 1.0000x reference)
//
#include <hip/hip_runtime.h>
#include <hip/hip_bf16.h>

#define BB 16
#define D1 1024
#define D2 1024
#define LL 512
#define TT 2048
#define LN_EPS 1e-5f

typedef unsigned short u16;
typedef __attribute__((ext_vector_type(8))) _Float16 half8;
typedef __attribute__((ext_vector_type(4))) float f32x4;
typedef __attribute__((ext_vector_type(4))) unsigned int u32x4;

__device__ __forceinline__ u16 f2h(float v) {
    _Float16 h = (_Float16)v;
    return *(u16*)&h;
}
__device__ __forceinline__ float h2f(u16 u) {
    return (float)(*(const _Float16*)&u);
}

__device__ __forceinline__ void gload_lds16(const void* g, void* l) {
    __builtin_amdgcn_global_load_lds((const __attribute__((address_space(1))) void*)g,
                                     (__attribute__((address_space(3))) void*)l, 16, 0, 0);
}

#define MEMFENCE asm volatile("" ::: "memory")
__device__ __forceinline__ void block_barrier() {
    MEMFENCE; __builtin_amdgcn_s_barrier(); MEMFENCE;
}

// ============================================================================
// BIG kernel: 256x256 tile, BK=64, 512 threads, 4-phase interleave. For QK^T.
// ============================================================================
template<int BIAS, int OMODE>
__global__ __launch_bounds__(512, 1) void nt_gemm(
    const u16* __restrict__ A, const u16* __restrict__ B,
    long sAb, long sBb, long sCb,
    int N, int Kd, int gx, int gy,
    const float* __restrict__ bias,
    void* __restrict__ out0,
    const float* __restrict__ resid, long sRb)
{
    __shared__ __align__(16) u16 smem[65536];

    const int nwg = gridDim.x;
    const int id = blockIdx.x;
    const int swz = (id & 7) * (nwg >> 3) + (id >> 3);
    const int bx = swz % gx;
    const int byz = swz / gx;
    const int by = byz % gy;
    const int b = byz / gy;

    const int tid = threadIdx.x;
    const long arow0 = (long)by * 256;
    const long brow0 = (long)bx * 256;
    const u16* Ab = A + (long)b * sAb + arow0 * Kd;
    const u16* Bb = B + (long)b * sBb + brow0 * Kd;

    const int wave = tid >> 6, lane = tid & 63;
    const int mh = wave >> 2;
    const int wm = mh * 128;
    const int wn = (wave & 3) * 64;
    const int lm = lane & 15, kg = lane >> 4;

    const int ntile = Kd >> 6;

    auto STAGE = [&](int buf, long k0) {
        u16* Ad = smem + buf * 32768;
        u16* Bd = Ad + 16384;
#pragma unroll
        for (int sw = 0; sw < 4; ++sw) {
            int idx = sw * 512 + tid;
            int m = idx >> 3, s = idx & 7;
            int gs = s ^ (m & 7);
            gload_lds16(Ab + k0 + (long)m * Kd + gs * 8, Ad + idx * 8);
        }
#pragma unroll
        for (int sw = 0; sw < 4; ++sw) {
            int idx = sw * 512 + tid;
            int m = idx >> 3, s = idx & 7;
            int gs = s ^ (m & 7);
            gload_lds16(Bb + k0 + (long)m * Kd + gs * 8, Bd + idx * 8);
        }
    };

    f32x4 acc[8][4];
#pragma unroll
    for (int i = 0; i < 8; ++i)
#pragma unroll
        for (int j = 0; j < 4; ++j) acc[i][j] = (f32x4){0.f, 0.f, 0.f, 0.f};

    STAGE(0, 0);
    if (ntile > 1) STAGE(1, 64);

    half8 a_[4][2], b_[2][2];

#define LOADA(ms_) do { \
    _Pragma("unroll") for (int f = 0; f < 4; ++f) \
    _Pragma("unroll") for (int kf = 0; kf < 2; ++kf) { \
        int mr = wm + (ms_) * 64 + f * 16 + lm; \
        int ss = (kf * 4 + kg) ^ (mr & 7); \
        a_[f][kf] = *(const half8*)(Ac + mr * 64 + ss * 8); } } while (0)
#define LOADB(ns_) do { \
    _Pragma("unroll") for (int f = 0; f < 2; ++f) \
    _Pragma("unroll") for (int kf = 0; kf < 2; ++kf) { \
        int nr = wn + (ns_) * 32 + f * 16 + lm; \
        int ss = (kf * 4 + kg) ^ (nr & 7); \
        b_[f][kf] = *(const half8*)(Bc + nr * 64 + ss * 8); } } while (0)
#define PH_MFMA(ms_, ns_) do { \
    block_barrier(); \
    asm volatile("s_waitcnt lgkmcnt(0)" ::: "memory"); \
    __builtin_amdgcn_sched_barrier(0); \
    __builtin_amdgcn_s_setprio(1); \
    _Pragma("unroll") for (int i = 0; i < 4; ++i) \
    _Pragma("unroll") for (int j = 0; j < 2; ++j) \
    _Pragma("unroll") for (int kf = 0; kf < 2; ++kf) \
        acc[(ms_) * 4 + i][(ns_) * 2 + j] = __builtin_amdgcn_mfma_f32_16x16x32_f16( \
            a_[i][kf], b_[j][kf], acc[(ms_) * 4 + i][(ns_) * 2 + j], 0, 0, 0); \
    __builtin_amdgcn_s_setprio(0); \
    block_barrier(); \
} while (0)

    for (int t = 0; t < ntile; ++t) {
        const int c = t & 1;
        const u16* Ac = smem + c * 32768;
        const u16* Bc = Ac + 16384;
        if (t + 1 < ntile) { asm volatile("s_waitcnt vmcnt(8)" ::: "memory"); }
        else               { asm volatile("s_waitcnt vmcnt(0)" ::: "memory"); }
        block_barrier();

        LOADA(0); LOADB(0); PH_MFMA(0, 0);
        LOADA(1);           PH_MFMA(1, 0);
        LOADB(1);           PH_MFMA(1, 1);
        LOADA(0);           PH_MFMA(0, 1);

        if (t + 2 < ntile) STAGE(c, (long)(t + 2) * 64);
    }
#undef LOADA
#undef LOADB
#undef PH_MFMA

    float* Cs = (float*)smem;
#pragma unroll
    for (int p = 0; p < 2; ++p) {
        __syncthreads();
        if (mh == p) {
#pragma unroll
            for (int ms = 0; ms < 2; ++ms)
#pragma unroll
                for (int i = 0; i < 4; ++i)
#pragma unroll
                    for (int ns = 0; ns < 2; ++ns)
#pragma unroll
                        for (int j = 0; j < 2; ++j)
#pragma unroll
                            for (int r = 0; r < 4; ++r) {
                                int row = ms * 64 + i * 16 + kg * 4 + r;
                                int col = wn + ns * 32 + j * 16 + lm;
                                Cs[row * 256 + (col ^ ((row & 7) << 2))] = acc[ms * 4 + i][ns * 2 + j][r];
                            }
        }
        __syncthreads();
#pragma unroll
        for (int it = 0; it < 16; ++it) {
            int elem = it * 512 + tid;
            int row = elem >> 6, c4 = elem & 63;
            int grow = (int)arow0 + p * 128 + row;
            int gcol = (int)brow0 + c4 * 4;
            f32x4 v = *(const f32x4*)&Cs[row * 256 + ((c4 ^ (row & 7)) << 2)];
            long off = (long)b * sCb + (long)grow * N + gcol;
            *(f32x4*)((float*)out0 + off) = v;
        }
    }
}

// ============================================================================
// SMALL kernel: 128x128 tile, BK=64, 256 threads, 32KB LDS (4+ blocks/CU).
// For memory-bound GEMMs with fp16 K-contig operands (PV, out-proj).
// LNS: accumulate sum/sumsq of C into lnsums[2] (per-batch) via atomics.
// ============================================================================
__device__ __forceinline__ void stage_tile_sm(const u16* __restrict__ g, int ldk, u16* lds, int tid) {
#pragma unroll
    for (int it = 0; it < 4; ++it) {
        int idx = it * 256 + tid;
        int m = idx >> 3, s = idx & 7;
        int gs = s ^ (m & 7);
        gload_lds16(g + (long)m * ldk + gs * 8, lds + idx * 8);
    }
}

template<int BIAS, int OMODE, int LNS>
__global__ __launch_bounds__(256, 4) void nt_gemm_sm(
    const u16* __restrict__ A, const u16* __restrict__ B,
    long sAb, long sBb, long sCb,
    int N, int Kd, int gx, int gy,
    const float* __restrict__ bias,
    void* __restrict__ out0,
    const float* __restrict__ resid, long sRb,
    float* __restrict__ lnsums)
{
    __shared__ __align__(16) u16 smem[2 * 128 * 64];
    u16* As = smem;
    u16* Bs = smem + 128 * 64;

    const int nwg = gridDim.x;
    const int id = blockIdx.x;
    const int swz = (id & 7) * (nwg >> 3) + (id >> 3);
    const int bx = swz % gx;
    const int byz = swz / gx;
    const int by = byz % gy;
    const int b = byz / gy;

    const int tid = threadIdx.x;
    const long arow0 = (long)by * 128;
    const long brow0 = (long)bx * 128;
    const u16* Ab = A + (long)b * sAb + arow0 * Kd;
    const u16* Bb = B + (long)b * sBb + brow0 * Kd;

    const int wave = tid >> 6, lane = tid & 63;
    const int wm = (wave >> 1) * 64, wn = (wave & 1) * 64;
    const int lm = lane & 15, kg = lane >> 4;

    f32x4 acc[4][4];
#pragma unroll
    for (int i = 0; i < 4; ++i)
#pragma unroll
        for (int j = 0; j < 4; ++j) acc[i][j] = (f32x4){0.f, 0.f, 0.f, 0.f};

    for (int k0 = 0; k0 < Kd; k0 += 64) {
        stage_tile_sm(Ab + k0, Kd, As, tid);
        stage_tile_sm(Bb + k0, Kd, Bs, tid);
        __syncthreads();
#pragma unroll
        for (int ks = 0; ks < 2; ++ks) {
            half8 af[4], bf[4];
#pragma unroll
            for (int f = 0; f < 4; ++f) {
                int mr = wm + f * 16 + lm;
                int as_ = (ks * 4 + kg) ^ (mr & 7);
                af[f] = *(const half8*)(As + mr * 64 + as_ * 8);
                int nr = wn + f * 16 + lm;
                int bs_ = (ks * 4 + kg) ^ (nr & 7);
                bf[f] = *(const half8*)(Bs + nr * 64 + bs_ * 8);
            }
#pragma unroll
            for (int i = 0; i < 4; ++i)
#pragma unroll
                for (int j = 0; j < 4; ++j)
                    acc[i][j] = __builtin_amdgcn_mfma_f32_16x16x32_f16(af[i], bf[j], acc[i][j], 0, 0, 0);
        }
        __syncthreads();
    }

    float ls = 0.f, lsq = 0.f;
    float* Cs = (float*)smem;
#pragma unroll
    for (int p = 0; p < 2; ++p) {
        if (p) __syncthreads();
        if (wm == p * 64) {
#pragma unroll
            for (int i = 0; i < 4; ++i)
#pragma unroll
                for (int j = 0; j < 4; ++j)
#pragma unroll
                    for (int r = 0; r < 4; ++r) {
                        int row = i * 16 + kg * 4 + r;
                        int col = wn + j * 16 + lm;
                        Cs[row * 128 + (col ^ ((row & 7) << 2))] = acc[i][j][r];
                    }
        }
        __syncthreads();
        if (OMODE == 0 || OMODE == 3) {
#pragma unroll
            for (int rr = 0; rr < 8; ++rr) {
                int elem = rr * 256 + tid;
                int row = elem >> 5, c4 = elem & 31;
                int grow = (int)arow0 + p * 64 + row;
                int gcol = (int)brow0 + c4 * 4;
                f32x4 v = *(const f32x4*)&Cs[row * 128 + ((c4 ^ (row & 7)) << 2)];
                if (BIAS == 1) v += bias[grow];
                if (BIAS == 2) v += *(const f32x4*)(bias + gcol);
                long off = (long)b * sCb + (long)grow * N + gcol;
                if (OMODE == 3) {
                    f32x4 rv = __builtin_nontemporal_load(
                        (const f32x4*)(resid + (long)b * sRb + (long)grow * N + gcol));
                    v += rv;
                    __builtin_nontemporal_store(v, (f32x4*)((float*)out0 + off));
                } else {
                    *(f32x4*)((float*)out0 + off) = v;
                }
            }
        } else {
#pragma unroll
            for (int rr = 0; rr < 4; ++rr) {
                int elem = rr * 256 + tid;
                int row = elem >> 4, c8 = elem & 15;
                int grow = (int)arow0 + p * 64 + row;
                int gcol = (int)brow0 + c8 * 8;
                int g0 = (c8 * 2) ^ (row & 7);
                int g1 = (c8 * 2 + 1) ^ (row & 7);
                f32x4 u0 = *(const f32x4*)&Cs[row * 128 + g0 * 4];
                f32x4 u1 = *(const f32x4*)&Cs[row * 128 + g1 * 4];
                float vv[8] = {u0.x, u0.y, u0.z, u0.w, u1.x, u1.y, u1.z, u1.w};
                if (BIAS == 1) {
                    float bb = bias[grow];
#pragma unroll
                    for (int q = 0; q < 8; ++q) vv[q] += bb;
                }
                if (BIAS == 2) {
#pragma unroll
                    for (int q = 0; q < 8; ++q) vv[q] += bias[gcol + q];
                }
                if (LNS) {
#pragma unroll
                    for (int q = 0; q < 8; ++q) { ls += vv[q]; lsq += vv[q] * vv[q]; }
                }
                union { u16 u[8]; u32x4 v4; } pk;
#pragma unroll
                for (int q = 0; q < 8; ++q) pk.u[q] = f2h(vv[q]);
                long off = (long)b * sCb + (long)grow * N + gcol;
                *(u32x4*)((u16*)out0 + off) = pk.v4;
            }
        }
    }
    if (LNS) {
#pragma unroll
        for (int off = 32; off; off >>= 1) {
            ls += __shfl_xor(ls, off, 64);
            lsq += __shfl_xor(lsq, off, 64);
        }
        __shared__ float rsum[8];
        if (lane == 0) { rsum[wave] = ls; rsum[4 + wave] = lsq; }
        __syncthreads();
        if (tid == 0) {
            atomicAdd(&lnsums[b * 2], rsum[0] + rsum[1] + rsum[2] + rsum[3]);
            atomicAdd(&lnsums[b * 2 + 1], rsum[4] + rsum[5] + rsum[6] + rsum[7]);
        }
    }
}

// ============================================================================
// PROJ kernel: fused transpose+convert+GEMM. 128x128 tile, BK=64, 256 thr.
// One operand is X fp32 [D][T] consumed transposed (reg-staged: coalesced
// f32x4 row loads -> f2h -> swizzled ds_write_b128); other is fp16 weights
// [N][K] via global_load_lds. TRA=1: A=X^T,B=W. TRA=0: A=W,B=X^T.
// Double-buffered; X regs for t+1 prefetched during tile t.
// ============================================================================
template<int TRA, int BIAS>
__global__ __launch_bounds__(256, 2) void proj_gemm(
    const float* __restrict__ Xf, const u16* __restrict__ Wh,
    long sXb, long sCb,
    int N, int Kd, int Tt, int gx, int gy,
    const float* __restrict__ bias,
    u16* __restrict__ out0)
{
    // [Xs0 16KB][Xs1 16KB][Ws0 16KB][Ws1 16KB] = 64 KiB
    __shared__ __align__(16) u16 smem[32768];

    const int nwg = gridDim.x;
    const int id = blockIdx.x;
    const int swz = (id & 7) * (nwg >> 3) + (id >> 3);
    const int bx = swz % gx;
    const int byz = swz / gx;
    const int by = byz % gy;
    const int b = byz / gy;

    const int tid = threadIdx.x;
    const long arow0 = (long)by * 128;
    const long brow0 = (long)bx * 128;
    const long x0 = TRA ? arow0 : brow0;        // t-range of X^T tile
    const long wrow0 = TRA ? brow0 : arow0;     // weight rows
    const float* Xb = Xf + (long)b * sXb + x0;
    const u16* Wb = Wh + wrow0 * Kd;

    const int wave = tid >> 6, lane = tid & 63;
    const int wm = (wave >> 1) * 64, wn = (wave & 1) * 64;
    const int lm = lane & 15, kg = lane >> 4;

    const int gq = tid >> 3;      // 0..31: t-quad group
    const int sl = tid & 7;       // 0..7: k-slot (8 d-values)

    const int ntile = Kd >> 6;

    auto WSTAGE = [&](int buf, long k0) {
        u16* Wd = smem + 16384 + buf * 8192;
#pragma unroll
        for (int it = 0; it < 4; ++it) {
            int idx = it * 256 + tid;
            int m = idx >> 3, s = idx & 7;
            int gs = s ^ (m & 7);
            gload_lds16(Wb + k0 + (long)m * Kd + gs * 8, Wd + idx * 8);
        }
    };

    f32x4 xr[8];
    auto XLOAD = [&](long k0) {
#pragma unroll
        for (int r = 0; r < 8; ++r)
            xr[r] = *(const f32x4*)(Xb + (k0 + sl * 8 + r) * Tt + gq * 4);
    };
    auto XWRITE = [&](int buf) {
        u16* Xd = smem + buf * 8192;
#pragma unroll
        for (int j = 0; j < 4; ++j) {
            int t = gq * 4 + j;
            union { u16 u[8]; u32x4 v4; } pk;
#pragma unroll
            for (int r = 0; r < 8; ++r) pk.u[r] = f2h(xr[r][j]);
            *(u32x4*)(Xd + t * 64 + (sl ^ (t & 7)) * 8) = pk.v4;
        }
    };

    f32x4 acc[4][4];
#pragma unroll
    for (int i = 0; i < 4; ++i)
#pragma unroll
        for (int j = 0; j < 4; ++j) acc[i][j] = (f32x4){0.f, 0.f, 0.f, 0.f};

    WSTAGE(0, 0);
    XLOAD(0);

    for (int t = 0; t < ntile; ++t) {
        const int c = t & 1;
        XWRITE(c);                               // auto-waits xr's vmcnt (covers W(t) too)
        if (t + 1 < ntile) {
            WSTAGE(c ^ 1, (long)(t + 1) * 64);
            XLOAD((long)(t + 1) * 64);
        }
        asm volatile("s_waitcnt lgkmcnt(0)" ::: "memory");
        block_barrier();

        const u16* Xc = smem + c * 8192;
        const u16* Wc = smem + 16384 + c * 8192;
        const u16* Ac = TRA ? Xc : Wc;
        const u16* Bc = TRA ? Wc : Xc;
#pragma unroll
        for (int ks = 0; ks < 2; ++ks) {
            half8 af[4], bf[4];
#pragma unroll
            for (int f = 0; f < 4; ++f) {
                int mr = wm + f * 16 + lm;
                int as_ = (ks * 4 + kg) ^ (mr & 7);
                af[f] = *(const half8*)(Ac + mr * 64 + as_ * 8);
                int nr = wn + f * 16 + lm;
                int bs_ = (ks * 4 + kg) ^ (nr & 7);
                bf[f] = *(const half8*)(Bc + nr * 64 + bs_ * 8);
            }
            __builtin_amdgcn_s_setprio(1);
#pragma unroll
            for (int i = 0; i < 4; ++i)
#pragma unroll
                for (int j = 0; j < 4; ++j)
                    acc[i][j] = __builtin_amdgcn_mfma_f32_16x16x32_f16(af[i], bf[j], acc[i][j], 0, 0, 0);
            __builtin_amdgcn_s_setprio(0);
        }
        block_barrier();
    }

    // epilogue: swizzled LDS stage, coalesced fp16 stores
    float* Cs = (float*)smem;
#pragma unroll
    for (int p = 0; p < 2; ++p) {
        if (p) __syncthreads();
        if (wm == p * 64) {
#pragma unroll
            for (int i = 0; i < 4; ++i)
#pragma unroll
                for (int j = 0; j < 4; ++j)
#pragma unroll
                    for (int r = 0; r < 4; ++r) {
                        int row = i * 16 + kg * 4 + r;
                        int col = wn + j * 16 + lm;
                        Cs[row * 128 + (col ^ ((row & 7) << 2))] = acc[i][j][r];
                    }
        }
        __syncthreads();
#pragma unroll
        for (int rr = 0; rr < 4; ++rr) {
            int elem = rr * 256 + tid;
            int row = elem >> 4, c8 = elem & 15;
            int grow = (int)arow0 + p * 64 + row;
            int gcol = (int)brow0 + c8 * 8;
            int g0 = (c8 * 2) ^ (row & 7);
            int g1 = (c8 * 2 + 1) ^ (row & 7);
            f32x4 u0 = *(const f32x4*)&Cs[row * 128 + g0 * 4];
            f32x4 u1 = *(const f32x4*)&Cs[row * 128 + g1 * 4];
            float vv[8] = {u0.x, u0.y, u0.z, u0.w, u1.x, u1.y, u1.z, u1.w};
            if (BIAS == 1) {
                float bb = bias[grow];
#pragma unroll
                for (int q = 0; q < 8; ++q) vv[q] += bb;
            }
            if (BIAS == 2) {
#pragma unroll
                for (int q = 0; q < 8; ++q) vv[q] += bias[gcol + q];
            }
            union { u16 u[8]; u32x4 v4; } pk;
#pragma unroll
            for (int q = 0; q < 8; ++q) pk.u[q] = f2h(vv[q]);
            long off = (long)b * sCb + (long)grow * N + gcol;
            *(u32x4*)(out0 + off) = pk.v4;
        }
    }
}

// fp32 [R][C] -> fp32 [C][R]
__global__ __launch_bounds__(256) void transpose_f32(const float* __restrict__ in,
                                                     float* __restrict__ out, int R, int C) {
    __shared__ float tile[64][65];
    int c0 = blockIdx.x * 64, r0 = blockIdx.y * 64;
    int tx = threadIdx.x & 63, ty = threadIdx.x >> 6;
#pragma unroll
    for (int i = 0; i < 64; i += 4)
        tile[ty + i][tx] = in[(long)(r0 + ty + i) * C + c0 + tx];
    __syncthreads();
#pragma unroll
    for (int i = 0; i < 64; i += 4)
        out[(long)(c0 + ty + i) * R + r0 + tx] = tile[tx][ty + i];
}

__global__ __launch_bounds__(256) void conv_w(const float* __restrict__ w,
                                              u16* __restrict__ h, int n) {
    int i = blockIdx.x * 256 + threadIdx.x;
    if (i < n) h[i] = f2h(w[i]);
}

// one block per score row (2048 cols), fp32 in (L3-resident), fp16 prob out
__global__ __launch_bounds__(256) void softmax_rows(const float* __restrict__ S, u16* __restrict__ P) {
    long row = (long)blockIdx.z * TT + blockIdx.x;
    const float* s = S + row * TT;
    u16* p = P + row * TT;
    int tid = threadIdx.x;
    f32x4 v0 = *(const f32x4*)(s + tid * 8);
    f32x4 v1 = *(const f32x4*)(s + tid * 8 + 4);
    float x[8] = {v0.x, v0.y, v0.z, v0.w, v1.x, v1.y, v1.z, v1.w};
    float m = x[0];
#pragma unroll
    for (int j = 1; j < 8; ++j) m = fmaxf(m, x[j]);
#pragma unroll
    for (int off = 32; off; off >>= 1) m = fmaxf(m, __shfl_xor(m, off, 64));
    __shared__ float red[8];
    int wave = tid >> 6, lane = tid & 63;
    if (lane == 0) red[wave] = m;
    __syncthreads();
    m = fmaxf(fmaxf(red[0], red[1]), fmaxf(red[2], red[3]));
    float e[8]; float sum = 0.f;
#pragma unroll
    for (int j = 0; j < 8; ++j) { e[j] = __expf(x[j] - m); sum += e[j]; }
#pragma unroll
    for (int off = 32; off; off >>= 1) sum += __shfl_xor(sum, off, 64);
    if (lane == 0) red[4 + wave] = sum;
    __syncthreads();
    sum = red[4] + red[5] + red[6] + red[7];
    float inv = 1.f / sum;
    union { u16 u[8]; u32x4 v4; } pk;
#pragma unroll
    for (int j = 0; j < 8; ++j) pk.u[j] = f2h(e[j] * inv);
    *(u32x4*)(p + tid * 8) = pk.v4;
}

__global__ void zero32(float* p) { p[threadIdx.x] = 0.f; }

__global__ __launch_bounds__(256) void ln_apply(const u16* __restrict__ TXp, const float* __restrict__ sums,
                                                const float* __restrict__ gT, const float* __restrict__ bT,
                                                u16* __restrict__ H) {
    int b = blockIdx.z;
    const float n = (float)(LL * TT);
    float mu = sums[b * 2] / n;
    float var = sums[b * 2 + 1] / n - mu * mu;
    float rstd = rsqrtf(var + LN_EPS);
    long base = (long)b * (LL * TT);
    long idx = ((long)blockIdx.x * 256 + threadIdx.x) * 8;
    u32x4 xv = *(const u32x4*)(TXp + base + idx);
    unsigned w[4] = {xv.x, xv.y, xv.z, xv.w};
    f32x4 g0 = *(const f32x4*)(gT + idx);
    f32x4 g1 = *(const f32x4*)(gT + idx + 4);
    f32x4 b0 = *(const f32x4*)(bT + idx);
    f32x4 b1 = *(const f32x4*)(bT + idx + 4);
    float g[8] = {g0.x, g0.y, g0.z, g0.w, g1.x, g1.y, g1.z, g1.w};
    float be[8] = {b0.x, b0.y, b0.z, b0.w, b1.x, b1.y, b1.z, b1.w};
    union { u16 u[8]; u32x4 v; } pk;
#pragma unroll
    for (int q = 0; q < 4; ++q) {
        float a = h2f((u16)(w[q] & 0xffff));
        float c = h2f((u16)(w[q] >> 16));
        float oa = fmaxf((a - mu) * rstd * g[q * 2] + be[q * 2], 0.f);
        float oc = fmaxf((c - mu) * rstd * g[q * 2 + 1] + be[q * 2 + 1], 0.f);
        pk.u[q * 2] = f2h(oa);
        pk.u[q * 2 + 1] = f2h(oc);
    }
    *(u32x4*)(H + base + idx) = pk.v;
}

extern "C" void kernel_launch(void* const* d_in, const int* in_sizes, int n_in,
                              void* d_out, int out_size, void* d_ws, size_t ws_size,
                              hipStream_t stream) {
    const float* input1  = (const float*)d_in[0];
    const float* input2  = (const float*)d_in[1];
    const float* theta_w = (const float*)d_in[2];
    const float* theta_b = (const float*)d_in[3];
    const float* phi_w   = (const float*)d_in[4];
    const float* phi_b   = (const float*)d_in[5];
    const float* g_w     = (const float*)d_in[6];
    const float* g_b     = (const float*)d_in[7];
    const float* ln_gamma= (const float*)d_in[8];
    const float* ln_beta = (const float*)d_in[9];
    const float* out_w   = (const float*)d_in[10];
    const float* out_b   = (const float*)d_in[11];
    float* out = (float*)d_out;

    char* ws = (char*)d_ws;
    const size_t MB = 1ull << 20;
    float* scores= (float*)(ws + 0);        // 64MB [4][T][T] fp32 (L3-resident)
    u16*  pmat   = (u16*)(ws + 64 * MB);    // 32MB [4][T][T] fp16 (per-chunk)
    u16*  Qf     = (u16*)(ws + 96 * MB);    // 32MB [B][T][L]
    u16*  Kf     = (u16*)(ws + 128 * MB);   // 32MB [B][T][L]
    u16*  Vt     = (u16*)(ws + 160 * MB);   // 32MB [B][L][T]
    u16*  TX     = (u16*)(ws + 192 * MB);   // 32MB [B][T][L] fp16
    u16*  H      = (u16*)(ws + 224 * MB);   // 32MB [B][T][L]
    u16*  thw    = (u16*)(ws + 256 * MB);   // 1MB each
    u16*  phw    = (u16*)(ws + 257 * MB);
    u16*  gww    = (u16*)(ws + 258 * MB);
    u16*  oww    = (u16*)(ws + 259 * MB);
    float* gammaT= (float*)(ws + 260 * MB); // 4MB [T][L]
    float* betaT = (float*)(ws + 264 * MB); // 4MB
    float* sums  = (float*)(ws + 268 * MB); // 128B

    dim3 blk(256), blk5(512);

    conv_w<<<dim3((LL * D2 + 255) / 256), blk, 0, stream>>>(theta_w, thw, LL * D2);
    conv_w<<<dim3((LL * D1 + 255) / 256), blk, 0, stream>>>(phi_w, phw, LL * D1);
    conv_w<<<dim3((LL * D1 + 255) / 256), blk, 0, stream>>>(g_w, gww, LL * D1);
    conv_w<<<dim3((D2 * LL + 255) / 256), blk, 0, stream>>>(out_w, oww, D2 * LL);
    transpose_f32<<<dim3(TT / 64, LL / 64, 1), blk, 0, stream>>>(ln_gamma, gammaT, LL, TT);
    transpose_f32<<<dim3(TT / 64, LL / 64, 1), blk, 0, stream>>>(ln_beta, betaT, LL, TT);
    zero32<<<dim3(1), dim3(32), 0, stream>>>(sums);

    // Projections (transpose fused): Q[t][l], K[t][l], Vt[l][t]
    proj_gemm<1, 2><<<dim3((LL / 128) * (TT / 128) * BB), blk, 0, stream>>>(
        input2, thw, (long)D2 * TT, (long)TT * LL, LL, D2, TT, LL / 128, TT / 128,
        theta_b, Qf);
    proj_gemm<1, 2><<<dim3((LL / 128) * (TT / 128) * BB), blk, 0, stream>>>(
        input1, phw, (long)D1 * TT, (long)TT * LL, LL, D1, TT, LL / 128, TT / 128,
        phi_b, Kf);
    proj_gemm<0, 1><<<dim3((TT / 128) * (LL / 128) * BB), blk, 0, stream>>>(
        input1, gww, (long)D1 * TT, (long)LL * TT, TT, D1, TT, TT / 128, LL / 128,
        g_b, Vt);

    // attention, 4 batches per chunk: QK^T (big) -> softmax -> PV (sm + LN sums)
    for (int c = 0; c < 4; ++c) {
        long qoff = (long)c * 4 * TT * LL;
        nt_gemm<0, 0><<<dim3((TT / 256) * (TT / 256) * 4), blk5, 0, stream>>>(
            Qf + qoff, Kf + qoff, (long)TT * LL, (long)TT * LL, (long)TT * TT,
            TT, LL, TT / 256, TT / 256, nullptr, scores, nullptr, 0);
        softmax_rows<<<dim3(TT, 1, 4), blk, 0, stream>>>(scores, pmat);
        nt_gemm_sm<0, 1, 1><<<dim3((LL / 128) * (TT / 128) * 4), blk, 0, stream>>>(
            pmat, Vt + (long)c * 4 * LL * TT, (long)TT * TT, (long)LL * TT, (long)TT * LL,
            LL, TT, LL / 128, TT / 128, nullptr, TX + qoff, nullptr, 0, sums + (long)c * 8);
    }

    ln_apply<<<dim3(512, 1, BB), blk, 0, stream>>>(TX, sums, gammaT, betaT, H);

    // out = out_w * h + out_b + input2
    nt_gemm_sm<1, 3, 0><<<dim3((TT / 128) * (D2 / 128) * BB), blk, 0, stream>>>(
        oww, H, 0, (long)TT * LL, (long)D2 * TT, TT, LL, TT / 128, D2 / 128,
        out_b, out, input2, (long)D2 * TT, nullptr);
}

// Round 10
// 627.963 us; speedup vs baseline: 1.1577x; 1.1577x over previous
//
#include <hip/hip_runtime.h>
#include <hip/hip_bf16.h>

#define BB 16
#define D1 1024
#define D2 1024
#define LL 512
#define TT 2048
#define LN_EPS 1e-5f

typedef unsigned short u16;
typedef __attribute__((ext_vector_type(8))) _Float16 half8;
typedef __attribute__((ext_vector_type(4))) float f32x4;
typedef __attribute__((ext_vector_type(4))) unsigned int u32x4;

__device__ __forceinline__ u16 f2h(float v) {
    _Float16 h = (_Float16)v;
    return *(u16*)&h;
}
__device__ __forceinline__ float h2f(u16 u) {
    return (float)(*(const _Float16*)&u);
}

__device__ __forceinline__ void gload_lds16(const void* g, void* l) {
    __builtin_amdgcn_global_load_lds((const __attribute__((address_space(1))) void*)g,
                                     (__attribute__((address_space(3))) void*)l, 16, 0, 0);
}

#define MEMFENCE asm volatile("" ::: "memory")
__device__ __forceinline__ void block_barrier() {
    MEMFENCE; __builtin_amdgcn_s_barrier(); MEMFENCE;
}

// ============================================================================
// BIG kernel (R5, measured best): 256x256 tile, BK=64, 512 threads (8 waves,
// 2Mx4N), double-buffered LDS, counted vmcnt(8). For projections + QK^T.
// ============================================================================
template<int BIAS, int OMODE>
__global__ __launch_bounds__(512, 2) void nt_gemm(
    const u16* __restrict__ A, const u16* __restrict__ B,
    long sAb, long sBb, long sCb,
    int N, int Kd, int gx, int gy,
    const float* __restrict__ bias,
    void* __restrict__ out0,
    const float* __restrict__ resid, long sRb)
{
    __shared__ __align__(16) u16 smem[65536];

    const int nwg = gridDim.x;
    const int id = blockIdx.x;
    const int swz = (id & 7) * (nwg >> 3) + (id >> 3);
    const int bx = swz % gx;
    const int byz = swz / gx;
    const int by = byz % gy;
    const int b = byz / gy;

    const int tid = threadIdx.x;
    const long arow0 = (long)by * 256;
    const long brow0 = (long)bx * 256;
    const u16* Ab = A + (long)b * sAb + arow0 * Kd;
    const u16* Bb = B + (long)b * sBb + brow0 * Kd;

    const int wave = tid >> 6, lane = tid & 63;
    const int wm = (wave >> 2) * 128, wn = (wave & 3) * 64;
    const int lm = lane & 15, kg = lane >> 4;

    const int m0 = tid >> 3, s0 = tid & 7;
    const int nt = Kd >> 6;

    auto STAGE = [&](int buf, long k0) {
        u16* Ad = smem + buf * 32768;
        u16* Bd = smem + buf * 32768 + 16384;
#pragma unroll
        for (int call = 0; call < 4; ++call) {
            int m = call * 64 + m0;
            int gs = s0 ^ (m & 7);
            gload_lds16(Ab + k0 + (long)m * Kd + gs * 8, Ad + (call * 512 + tid) * 8);
        }
#pragma unroll
        for (int call = 0; call < 4; ++call) {
            int m = call * 64 + m0;
            int gs = s0 ^ (m & 7);
            gload_lds16(Bb + k0 + (long)m * Kd + gs * 8, Bd + (call * 512 + tid) * 8);
        }
    };

    f32x4 acc[8][4];
#pragma unroll
    for (int i = 0; i < 8; ++i)
#pragma unroll
        for (int j = 0; j < 4; ++j) acc[i][j] = (f32x4){0.f, 0.f, 0.f, 0.f};

    STAGE(0, 0);
    if (nt > 1) STAGE(1, 64);

    for (int t = 0; t < nt; ++t) {
        const int cur = t & 1;
        if (t + 1 < nt) { asm volatile("s_waitcnt vmcnt(8)" ::: "memory"); }
        else           { asm volatile("s_waitcnt vmcnt(0)" ::: "memory"); }
        block_barrier();

        const u16* Ac = smem + cur * 32768;
        const u16* Bc = smem + cur * 32768 + 16384;

        half8 bf[4][2];
#pragma unroll
        for (int f = 0; f < 4; ++f)
#pragma unroll
            for (int kf = 0; kf < 2; ++kf) {
                int nr = wn + f * 16 + lm;
                int ss = (kf * 4 + kg) ^ (nr & 7);
                bf[f][kf] = *(const half8*)(Bc + nr * 64 + ss * 8);
            }
#pragma unroll
        for (int mh = 0; mh < 2; ++mh) {
            half8 af[4][2];
#pragma unroll
            for (int f = 0; f < 4; ++f)
#pragma unroll
                for (int kf = 0; kf < 2; ++kf) {
                    int mr = wm + mh * 64 + f * 16 + lm;
                    int ss = (kf * 4 + kg) ^ (mr & 7);
                    af[f][kf] = *(const half8*)(Ac + mr * 64 + ss * 8);
                }
            __builtin_amdgcn_s_setprio(1);
#pragma unroll
            for (int f = 0; f < 4; ++f)
#pragma unroll
                for (int j = 0; j < 4; ++j)
#pragma unroll
                    for (int kf = 0; kf < 2; ++kf)
                        acc[mh * 4 + f][j] = __builtin_amdgcn_mfma_f32_16x16x32_f16(
                            af[f][kf], bf[j][kf], acc[mh * 4 + f][j], 0, 0, 0);
            __builtin_amdgcn_s_setprio(0);
        }
        block_barrier();
        if (t + 2 < nt) STAGE(cur, (long)(t + 2) * 64);
    }

    // epilogue: LDS-staged (swizzled), coalesced stores; two 128-row passes
    float* Cs = (float*)smem;
#pragma unroll
    for (int p = 0; p < 2; ++p) {
        __syncthreads();
        if (wm == p * 128) {
#pragma unroll
            for (int i = 0; i < 8; ++i)
#pragma unroll
                for (int j = 0; j < 4; ++j)
#pragma unroll
                    for (int r = 0; r < 4; ++r) {
                        int row = i * 16 + kg * 4 + r;
                        int col = wn + j * 16 + lm;
                        Cs[row * 256 + (col ^ ((row & 7) << 2))] = acc[i][j][r];
                    }
        }
        __syncthreads();
        if (OMODE == 0 || OMODE == 3) {
#pragma unroll
            for (int it = 0; it < 16; ++it) {
                int elem = it * 512 + tid;
                int row = elem >> 6, c4 = elem & 63;
                int grow = (int)arow0 + p * 128 + row;
                int gcol = (int)brow0 + c4 * 4;
                f32x4 v = *(const f32x4*)&Cs[row * 256 + ((c4 ^ (row & 7)) << 2)];
                if (BIAS == 1) v += bias[grow];
                if (BIAS == 2) v += *(const f32x4*)(bias + gcol);
                long off = (long)b * sCb + (long)grow * N + gcol;
                if (OMODE == 3) {
                    f32x4 rv = __builtin_nontemporal_load(
                        (const f32x4*)(resid + (long)b * sRb + (long)grow * N + gcol));
                    v += rv;
                    __builtin_nontemporal_store(v, (f32x4*)((float*)out0 + off));
                } else {
                    *(f32x4*)((float*)out0 + off) = v;
                }
            }
        } else {
#pragma unroll
            for (int it = 0; it < 8; ++it) {
                int elem = it * 512 + tid;
                int row = elem >> 5, c8 = elem & 31;
                int grow = (int)arow0 + p * 128 + row;
                int gcol = (int)brow0 + c8 * 8;
                int g0 = (c8 * 2) ^ (row & 7);
                int g1 = (c8 * 2 + 1) ^ (row & 7);
                f32x4 u0 = *(const f32x4*)&Cs[row * 256 + g0 * 4];
                f32x4 u1 = *(const f32x4*)&Cs[row * 256 + g1 * 4];
                float vv[8] = {u0.x, u0.y, u0.z, u0.w, u1.x, u1.y, u1.z, u1.w};
                if (BIAS == 1) {
                    float bb = bias[grow];
#pragma unroll
                    for (int q = 0; q < 8; ++q) vv[q] += bb;
                }
                if (BIAS == 2) {
#pragma unroll
                    for (int q = 0; q < 8; ++q) vv[q] += bias[gcol + q];
                }
                union { u16 u[8]; u32x4 v4; } pk;
#pragma unroll
                for (int q = 0; q < 8; ++q) pk.u[q] = f2h(vv[q]);
                long off = (long)b * sCb + (long)grow * N + gcol;
                *(u32x4*)((u16*)out0 + off) = pk.v4;
            }
        }
    }
}

// ============================================================================
// SMALL kernel (R8): 128x128, BK=64, 256 thr, 32KB LDS (4 blocks/CU).
// For memory-bound GEMMs (PV, out-proj). LNS: fused LayerNorm sum/sumsq.
// ============================================================================
__device__ __forceinline__ void stage_tile_sm(const u16* __restrict__ g, int ldk, u16* lds, int tid) {
#pragma unroll
    for (int it = 0; it < 4; ++it) {
        int idx = it * 256 + tid;
        int m = idx >> 3, s = idx & 7;
        int gs = s ^ (m & 7);
        gload_lds16(g + (long)m * ldk + gs * 8, lds + idx * 8);
    }
}

template<int BIAS, int OMODE, int LNS>
__global__ __launch_bounds__(256, 4) void nt_gemm_sm(
    const u16* __restrict__ A, const u16* __restrict__ B,
    long sAb, long sBb, long sCb,
    int N, int Kd, int gx, int gy,
    const float* __restrict__ bias,
    void* __restrict__ out0,
    const float* __restrict__ resid, long sRb,
    float* __restrict__ lnsums)
{
    __shared__ __align__(16) u16 smem[2 * 128 * 64];
    u16* As = smem;
    u16* Bs = smem + 128 * 64;

    const int nwg = gridDim.x;
    const int id = blockIdx.x;
    const int swz = (id & 7) * (nwg >> 3) + (id >> 3);
    const int bx = swz % gx;
    const int byz = swz / gx;
    const int by = byz % gy;
    const int b = byz / gy;

    const int tid = threadIdx.x;
    const long arow0 = (long)by * 128;
    const long brow0 = (long)bx * 128;
    const u16* Ab = A + (long)b * sAb + arow0 * Kd;
    const u16* Bb = B + (long)b * sBb + brow0 * Kd;

    const int wave = tid >> 6, lane = tid & 63;
    const int wm = (wave >> 1) * 64, wn = (wave & 1) * 64;
    const int lm = lane & 15, kg = lane >> 4;

    f32x4 acc[4][4];
#pragma unroll
    for (int i = 0; i < 4; ++i)
#pragma unroll
        for (int j = 0; j < 4; ++j) acc[i][j] = (f32x4){0.f, 0.f, 0.f, 0.f};

    for (int k0 = 0; k0 < Kd; k0 += 64) {
        stage_tile_sm(Ab + k0, Kd, As, tid);
        stage_tile_sm(Bb + k0, Kd, Bs, tid);
        __syncthreads();
#pragma unroll
        for (int ks = 0; ks < 2; ++ks) {
            half8 af[4], bf[4];
#pragma unroll
            for (int f = 0; f < 4; ++f) {
                int mr = wm + f * 16 + lm;
                int as_ = (ks * 4 + kg) ^ (mr & 7);
                af[f] = *(const half8*)(As + mr * 64 + as_ * 8);
                int nr = wn + f * 16 + lm;
                int bs_ = (ks * 4 + kg) ^ (nr & 7);
                bf[f] = *(const half8*)(Bs + nr * 64 + bs_ * 8);
            }
#pragma unroll
            for (int i = 0; i < 4; ++i)
#pragma unroll
                for (int j = 0; j < 4; ++j)
                    acc[i][j] = __builtin_amdgcn_mfma_f32_16x16x32_f16(af[i], bf[j], acc[i][j], 0, 0, 0);
        }
        __syncthreads();
    }

    float ls = 0.f, lsq = 0.f;
    float* Cs = (float*)smem;
#pragma unroll
    for (int p = 0; p < 2; ++p) {
        if (p) __syncthreads();
        if (wm == p * 64) {
#pragma unroll
            for (int i = 0; i < 4; ++i)
#pragma unroll
                for (int j = 0; j < 4; ++j)
#pragma unroll
                    for (int r = 0; r < 4; ++r) {
                        int row = i * 16 + kg * 4 + r;
                        int col = wn + j * 16 + lm;
                        Cs[row * 128 + (col ^ ((row & 7) << 2))] = acc[i][j][r];
                    }
        }
        __syncthreads();
        if (OMODE == 0 || OMODE == 3) {
#pragma unroll
            for (int rr = 0; rr < 8; ++rr) {
                int elem = rr * 256 + tid;
                int row = elem >> 5, c4 = elem & 31;
                int grow = (int)arow0 + p * 64 + row;
                int gcol = (int)brow0 + c4 * 4;
                f32x4 v = *(const f32x4*)&Cs[row * 128 + ((c4 ^ (row & 7)) << 2)];
                if (BIAS == 1) v += bias[grow];
                if (BIAS == 2) v += *(const f32x4*)(bias + gcol);
                long off = (long)b * sCb + (long)grow * N + gcol;
                if (OMODE == 3) {
                    f32x4 rv = __builtin_nontemporal_load(
                        (const f32x4*)(resid + (long)b * sRb + (long)grow * N + gcol));
                    v += rv;
                    __builtin_nontemporal_store(v, (f32x4*)((float*)out0 + off));
                } else {
                    *(f32x4*)((float*)out0 + off) = v;
                }
            }
        } else {
#pragma unroll
            for (int rr = 0; rr < 4; ++rr) {
                int elem = rr * 256 + tid;
                int row = elem >> 4, c8 = elem & 15;
                int grow = (int)arow0 + p * 64 + row;
                int gcol = (int)brow0 + c8 * 8;
                int g0 = (c8 * 2) ^ (row & 7);
                int g1 = (c8 * 2 + 1) ^ (row & 7);
                f32x4 u0 = *(const f32x4*)&Cs[row * 128 + g0 * 4];
                f32x4 u1 = *(const f32x4*)&Cs[row * 128 + g1 * 4];
                float vv[8] = {u0.x, u0.y, u0.z, u0.w, u1.x, u1.y, u1.z, u1.w};
                if (BIAS == 1) {
                    float bb = bias[grow];
#pragma unroll
                    for (int q = 0; q < 8; ++q) vv[q] += bb;
                }
                if (BIAS == 2) {
#pragma unroll
                    for (int q = 0; q < 8; ++q) vv[q] += bias[gcol + q];
                }
                if (LNS) {
#pragma unroll
                    for (int q = 0; q < 8; ++q) { ls += vv[q]; lsq += vv[q] * vv[q]; }
                }
                union { u16 u[8]; u32x4 v4; } pk;
#pragma unroll
                for (int q = 0; q < 8; ++q) pk.u[q] = f2h(vv[q]);
                long off = (long)b * sCb + (long)grow * N + gcol;
                *(u32x4*)((u16*)out0 + off) = pk.v4;
            }
        }
    }
    if (LNS) {
#pragma unroll
        for (int off = 32; off; off >>= 1) {
            ls += __shfl_xor(ls, off, 64);
            lsq += __shfl_xor(lsq, off, 64);
        }
        __shared__ float rsum[8];
        if (lane == 0) { rsum[wave] = ls; rsum[4 + wave] = lsq; }
        __syncthreads();
        if (tid == 0) {
            atomicAdd(&lnsums[b * 2], rsum[0] + rsum[1] + rsum[2] + rsum[3]);
            atomicAdd(&lnsums[b * 2 + 1], rsum[4] + rsum[5] + rsum[6] + rsum[7]);
        }
    }
}

// fp32 [D][T] (per batch) -> fp16 [T][D]
__global__ __launch_bounds__(256) void transpose_h(const float* __restrict__ in,
                                                   u16* __restrict__ o16, int D, int T) {
    __shared__ float tile[64][65];
    int b = blockIdx.z;
    const float* src = in + (long)b * D * T;
    long obase = (long)b * D * T;
    int t0 = blockIdx.x * 64, d0 = blockIdx.y * 64;
    int tx = threadIdx.x & 63, ty = threadIdx.x >> 6;
#pragma unroll
    for (int i = 0; i < 64; i += 4)
        tile[ty + i][tx] = __builtin_nontemporal_load(&src[(long)(d0 + ty + i) * T + t0 + tx]);
    __syncthreads();
#pragma unroll
    for (int i = 0; i < 64; i += 4) {
        long o = obase + (long)(t0 + ty + i) * D + d0 + tx;
        o16[o] = f2h(tile[tx][ty + i]);
    }
}

// fp32 [R][C] -> fp32 [C][R]
__global__ __launch_bounds__(256) void transpose_f32(const float* __restrict__ in,
                                                     float* __restrict__ out, int R, int C) {
    __shared__ float tile[64][65];
    int c0 = blockIdx.x * 64, r0 = blockIdx.y * 64;
    int tx = threadIdx.x & 63, ty = threadIdx.x >> 6;
#pragma unroll
    for (int i = 0; i < 64; i += 4)
        tile[ty + i][tx] = in[(long)(r0 + ty + i) * C + c0 + tx];
    __syncthreads();
#pragma unroll
    for (int i = 0; i < 64; i += 4)
        out[(long)(c0 + ty + i) * R + r0 + tx] = tile[tx][ty + i];
}

__global__ __launch_bounds__(256) void conv_w(const float* __restrict__ w,
                                              u16* __restrict__ h, int n) {
    int i = blockIdx.x * 256 + threadIdx.x;
    if (i < n) h[i] = f2h(w[i]);
}

// one block per score row (2048 cols), fp32 in (L3-resident), fp16 prob out
__global__ __launch_bounds__(256) void softmax_rows(const float* __restrict__ S, u16* __restrict__ P) {
    long row = (long)blockIdx.z * TT + blockIdx.x;
    const float* s = S + row * TT;
    u16* p = P + row * TT;
    int tid = threadIdx.x;
    f32x4 v0 = *(const f32x4*)(s + tid * 8);
    f32x4 v1 = *(const f32x4*)(s + tid * 8 + 4);
    float x[8] = {v0.x, v0.y, v0.z, v0.w, v1.x, v1.y, v1.z, v1.w};
    float m = x[0];
#pragma unroll
    for (int j = 1; j < 8; ++j) m = fmaxf(m, x[j]);
#pragma unroll
    for (int off = 32; off; off >>= 1) m = fmaxf(m, __shfl_xor(m, off, 64));
    __shared__ float red[8];
    int wave = tid >> 6, lane = tid & 63;
    if (lane == 0) red[wave] = m;
    __syncthreads();
    m = fmaxf(fmaxf(red[0], red[1]), fmaxf(red[2], red[3]));
    float e[8]; float sum = 0.f;
#pragma unroll
    for (int j = 0; j < 8; ++j) { e[j] = __expf(x[j] - m); sum += e[j]; }
#pragma unroll
    for (int off = 32; off; off >>= 1) sum += __shfl_xor(sum, off, 64);
    if (lane == 0) red[4 + wave] = sum;
    __syncthreads();
    sum = red[4] + red[5] + red[6] + red[7];
    float inv = 1.f / sum;
    union { u16 u[8]; u32x4 v4; } pk;
#pragma unroll
    for (int j = 0; j < 8; ++j) pk.u[j] = f2h(e[j] * inv);
    *(u32x4*)(p + tid * 8) = pk.v4;
}

__global__ void zero32(float* p) { p[threadIdx.x] = 0.f; }

__global__ __launch_bounds__(256) void ln_apply(const u16* __restrict__ TXp, const float* __restrict__ sums,
                                                const float* __restrict__ gT, const float* __restrict__ bT,
                                                u16* __restrict__ H) {
    int b = blockIdx.z;
    const float n = (float)(LL * TT);
    float mu = sums[b * 2] / n;
    float var = sums[b * 2 + 1] / n - mu * mu;
    float rstd = rsqrtf(var + LN_EPS);
    long base = (long)b * (LL * TT);
    long idx = ((long)blockIdx.x * 256 + threadIdx.x) * 8;
    u32x4 xv = *(const u32x4*)(TXp + base + idx);
    unsigned w[4] = {xv.x, xv.y, xv.z, xv.w};
    f32x4 g0 = *(const f32x4*)(gT + idx);
    f32x4 g1 = *(const f32x4*)(gT + idx + 4);
    f32x4 b0 = *(const f32x4*)(bT + idx);
    f32x4 b1 = *(const f32x4*)(bT + idx + 4);
    float g[8] = {g0.x, g0.y, g0.z, g0.w, g1.x, g1.y, g1.z, g1.w};
    float be[8] = {b0.x, b0.y, b0.z, b0.w, b1.x, b1.y, b1.z, b1.w};
    union { u16 u[8]; u32x4 v; } pk;
#pragma unroll
    for (int q = 0; q < 4; ++q) {
        float a = h2f((u16)(w[q] & 0xffff));
        float c = h2f((u16)(w[q] >> 16));
        float oa = fmaxf((a - mu) * rstd * g[q * 2] + be[q * 2], 0.f);
        float oc = fmaxf((c - mu) * rstd * g[q * 2 + 1] + be[q * 2 + 1], 0.f);
        pk.u[q * 2] = f2h(oa);
        pk.u[q * 2 + 1] = f2h(oc);
    }
    *(u32x4*)(H + base + idx) = pk.v;
}

extern "C" void kernel_launch(void* const* d_in, const int* in_sizes, int n_in,
                              void* d_out, int out_size, void* d_ws, size_t ws_size,
                              hipStream_t stream) {
    const float* input1  = (const float*)d_in[0];
    const float* input2  = (const float*)d_in[1];
    const float* theta_w = (const float*)d_in[2];
    const float* theta_b = (const float*)d_in[3];
    const float* phi_w   = (const float*)d_in[4];
    const float* phi_b   = (const float*)d_in[5];
    const float* g_w     = (const float*)d_in[6];
    const float* g_b     = (const float*)d_in[7];
    const float* ln_gamma= (const float*)d_in[8];
    const float* ln_beta = (const float*)d_in[9];
    const float* out_w   = (const float*)d_in[10];
    const float* out_b   = (const float*)d_in[11];
    float* out = (float*)d_out;

    char* ws = (char*)d_ws;
    const size_t MB = 1ull << 20;
    u16*  Xt     = (u16*)(ws + 0);          // 64MB [B][T][1024] fp16 (dead after projections)
    float* scores= (float*)(ws + 0);        // 64MB [4][T][T] fp32 (reuses Xt, L3-resident)
    u16*  pmat   = (u16*)(ws + 64 * MB);    // 32MB [4][T][T] fp16 (per-chunk, L3-resident)
    u16*  Qf     = (u16*)(ws + 96 * MB);    // 32MB [B][T][L]
    u16*  Kf     = (u16*)(ws + 128 * MB);   // 32MB [B][T][L]
    u16*  Vt     = (u16*)(ws + 160 * MB);   // 32MB [B][L][T]
    u16*  TX     = (u16*)(ws + 192 * MB);   // 32MB [B][T][L] fp16
    u16*  H      = (u16*)(ws + 224 * MB);   // 32MB [B][T][L]
    u16*  thw    = (u16*)(ws + 256 * MB);   // 1MB each
    u16*  phw    = (u16*)(ws + 257 * MB);
    u16*  gww    = (u16*)(ws + 258 * MB);
    u16*  oww    = (u16*)(ws + 259 * MB);
    float* gammaT= (float*)(ws + 260 * MB); // 4MB [T][L]
    float* betaT = (float*)(ws + 264 * MB); // 4MB
    float* sums  = (float*)(ws + 268 * MB); // 128B

    dim3 blk(256), blk5(512);

    conv_w<<<dim3((LL * D2 + 255) / 256), blk, 0, stream>>>(theta_w, thw, LL * D2);
    conv_w<<<dim3((LL * D1 + 255) / 256), blk, 0, stream>>>(phi_w, phw, LL * D1);
    conv_w<<<dim3((LL * D1 + 255) / 256), blk, 0, stream>>>(g_w, gww, LL * D1);
    conv_w<<<dim3((D2 * LL + 255) / 256), blk, 0, stream>>>(out_w, oww, D2 * LL);
    transpose_f32<<<dim3(TT / 64, LL / 64, 1), blk, 0, stream>>>(ln_gamma, gammaT, LL, TT);
    transpose_f32<<<dim3(TT / 64, LL / 64, 1), blk, 0, stream>>>(ln_beta, betaT, LL, TT);
    zero32<<<dim3(1), dim3(32), 0, stream>>>(sums);

    // Q = theta(input2)
    transpose_h<<<dim3(TT / 64, D2 / 64, BB), blk, 0, stream>>>(input2, Xt, D2, TT);
    nt_gemm<2, 1><<<dim3((LL / 256) * (TT / 256) * BB), blk5, 0, stream>>>(
        Xt, thw, (long)TT * D2, 0, (long)TT * LL, LL, D2, LL / 256, TT / 256,
        theta_b, Qf, nullptr, 0);

    // K = phi(input1), V^T = g(input1)
    transpose_h<<<dim3(TT / 64, D1 / 64, BB), blk, 0, stream>>>(input1, Xt, D1, TT);
    nt_gemm<2, 1><<<dim3((LL / 256) * (TT / 256) * BB), blk5, 0, stream>>>(
        Xt, phw, (long)TT * D1, 0, (long)TT * LL, LL, D1, LL / 256, TT / 256,
        phi_b, Kf, nullptr, 0);
    nt_gemm<1, 1><<<dim3((TT / 256) * (LL / 256) * BB), blk5, 0, stream>>>(
        gww, Xt, 0, (long)TT * D1, (long)LL * TT, TT, D1, TT / 256, LL / 256,
        g_b, Vt, nullptr, 0);

    // attention, 4 batches per chunk: QK^T (big) -> softmax -> PV (sm, LN fused)
    for (int c = 0; c < 4; ++c) {
        long qoff = (long)c * 4 * TT * LL;
        nt_gemm<0, 0><<<dim3((TT / 256) * (TT / 256) * 4), blk5, 0, stream>>>(
            Qf + qoff, Kf + qoff, (long)TT * LL, (long)TT * LL, (long)TT * TT,
            TT, LL, TT / 256, TT / 256, nullptr, scores, nullptr, 0);
        softmax_rows<<<dim3(TT, 1, 4), blk, 0, stream>>>(scores, pmat);
        nt_gemm_sm<0, 1, 1><<<dim3((LL / 128) * (TT / 128) * 4), blk, 0, stream>>>(
            pmat, Vt + (long)c * 4 * LL * TT, (long)TT * TT, (long)LL * TT, (long)TT * LL,
            LL, TT, LL / 128, TT / 128, nullptr, TX + qoff, nullptr, 0, sums + (long)c * 8);
    }

    ln_apply<<<dim3(512, 1, BB), blk, 0, stream>>>(TX, sums, gammaT, betaT, H);

    // out = out_w * h + out_b + input2
    nt_gemm_sm<1, 3, 0><<<dim3((TT / 128) * (D2 / 128) * BB), blk, 0, stream>>>(
        oww, H, 0, (long)TT * LL, (long)D2 * TT, TT, LL, TT / 128, D2 / 128,
        out_b, out, input2, (long)D2 * TT, nullptr);
}

// Round 11
// 566.345 us; speedup vs baseline: 1.2837x; 1.1088x over previous
//
#include <hip/hip_runtime.h>
#include <hip/hip_bf16.h>

#define BB 16
#define D1 1024
#define D2 1024
#define LL 512
#define TT 2048
#define LN_EPS 1e-5f

typedef unsigned short u16;
typedef __attribute__((ext_vector_type(8))) _Float16 half8;
typedef __attribute__((ext_vector_type(4))) float f32x4;
typedef __attribute__((ext_vector_type(4))) unsigned int u32x4;

__device__ __forceinline__ u16 f2h(float v) {
    _Float16 h = (_Float16)v;
    return *(u16*)&h;
}
__device__ __forceinline__ float h2f(u16 u) {
    return (float)(*(const _Float16*)&u);
}

__device__ __forceinline__ void gload_lds16(const void* g, void* l) {
    __builtin_amdgcn_global_load_lds((const __attribute__((address_space(1))) void*)g,
                                     (__attribute__((address_space(3))) void*)l, 16, 0, 0);
}

#define MEMFENCE asm volatile("" ::: "memory")
__device__ __forceinline__ void block_barrier() {
    MEMFENCE; __builtin_amdgcn_s_barrier(); MEMFENCE;
}

// ============================================================================
// BIG kernel (the 586-us config): 256x256 tile, BK=64, 512 threads (8 waves,
// 2Mx4N), double-buffered LDS, counted vmcnt(8). Projections + QK^T + PV.
// LNS=1 (with OMODE=1): accumulate LayerNorm sum/sumsq of C per batch.
// ============================================================================
template<int BIAS, int OMODE, int LNS>
__global__ __launch_bounds__(512, 2) void nt_gemm(
    const u16* __restrict__ A, const u16* __restrict__ B,
    long sAb, long sBb, long sCb,
    int N, int Kd, int gx, int gy,
    const float* __restrict__ bias,
    void* __restrict__ out0,
    const float* __restrict__ resid, long sRb,
    float* __restrict__ lnsums)
{
    __shared__ __align__(16) u16 smem[65536];

    const int nwg = gridDim.x;
    const int id = blockIdx.x;
    const int swz = (id & 7) * (nwg >> 3) + (id >> 3);
    const int bx = swz % gx;
    const int byz = swz / gx;
    const int by = byz % gy;
    const int b = byz / gy;

    const int tid = threadIdx.x;
    const long arow0 = (long)by * 256;
    const long brow0 = (long)bx * 256;
    const u16* Ab = A + (long)b * sAb + arow0 * Kd;
    const u16* Bb = B + (long)b * sBb + brow0 * Kd;

    const int wave = tid >> 6, lane = tid & 63;
    const int wm = (wave >> 2) * 128, wn = (wave & 3) * 64;
    const int lm = lane & 15, kg = lane >> 4;

    const int m0 = tid >> 3, s0 = tid & 7;
    const int nt = Kd >> 6;

    auto STAGE = [&](int buf, long k0) {
        u16* Ad = smem + buf * 32768;
        u16* Bd = smem + buf * 32768 + 16384;
#pragma unroll
        for (int call = 0; call < 4; ++call) {
            int m = call * 64 + m0;
            int gs = s0 ^ (m & 7);
            gload_lds16(Ab + k0 + (long)m * Kd + gs * 8, Ad + (call * 512 + tid) * 8);
        }
#pragma unroll
        for (int call = 0; call < 4; ++call) {
            int m = call * 64 + m0;
            int gs = s0 ^ (m & 7);
            gload_lds16(Bb + k0 + (long)m * Kd + gs * 8, Bd + (call * 512 + tid) * 8);
        }
    };

    f32x4 acc[8][4];
#pragma unroll
    for (int i = 0; i < 8; ++i)
#pragma unroll
        for (int j = 0; j < 4; ++j) acc[i][j] = (f32x4){0.f, 0.f, 0.f, 0.f};

    STAGE(0, 0);
    if (nt > 1) STAGE(1, 64);

    for (int t = 0; t < nt; ++t) {
        const int cur = t & 1;
        if (t + 1 < nt) { asm volatile("s_waitcnt vmcnt(8)" ::: "memory"); }
        else           { asm volatile("s_waitcnt vmcnt(0)" ::: "memory"); }
        block_barrier();

        const u16* Ac = smem + cur * 32768;
        const u16* Bc = smem + cur * 32768 + 16384;

        half8 bf[4][2];
#pragma unroll
        for (int f = 0; f < 4; ++f)
#pragma unroll
            for (int kf = 0; kf < 2; ++kf) {
                int nr = wn + f * 16 + lm;
                int ss = (kf * 4 + kg) ^ (nr & 7);
                bf[f][kf] = *(const half8*)(Bc + nr * 64 + ss * 8);
            }
#pragma unroll
        for (int mh = 0; mh < 2; ++mh) {
            half8 af[4][2];
#pragma unroll
            for (int f = 0; f < 4; ++f)
#pragma unroll
                for (int kf = 0; kf < 2; ++kf) {
                    int mr = wm + mh * 64 + f * 16 + lm;
                    int ss = (kf * 4 + kg) ^ (mr & 7);
                    af[f][kf] = *(const half8*)(Ac + mr * 64 + ss * 8);
                }
            __builtin_amdgcn_s_setprio(1);
#pragma unroll
            for (int f = 0; f < 4; ++f)
#pragma unroll
                for (int j = 0; j < 4; ++j)
#pragma unroll
                    for (int kf = 0; kf < 2; ++kf)
                        acc[mh * 4 + f][j] = __builtin_amdgcn_mfma_f32_16x16x32_f16(
                            af[f][kf], bf[j][kf], acc[mh * 4 + f][j], 0, 0, 0);
            __builtin_amdgcn_s_setprio(0);
        }
        block_barrier();
        if (t + 2 < nt) STAGE(cur, (long)(t + 2) * 64);
    }

    // ---- epilogue: LDS-staged (swizzled), coalesced nt stores; two 128-row passes ----
    float ls = 0.f, lsq = 0.f;
    float* Cs = (float*)smem;   // 128 x 256 fp32 = 128 KB
#pragma unroll
    for (int p = 0; p < 2; ++p) {
        __syncthreads();
        if (wm == p * 128) {
#pragma unroll
            for (int i = 0; i < 8; ++i)
#pragma unroll
                for (int j = 0; j < 4; ++j)
#pragma unroll
                    for (int r = 0; r < 4; ++r) {
                        int row = i * 16 + kg * 4 + r;
                        int col = wn + j * 16 + lm;
                        Cs[row * 256 + (col ^ ((row & 7) << 2))] = acc[i][j][r];
                    }
        }
        __syncthreads();
        if (OMODE == 0 || OMODE == 3) {
#pragma unroll
            for (int it = 0; it < 16; ++it) {
                int elem = it * 512 + tid;
                int row = elem >> 6, c4 = elem & 63;
                int grow = (int)arow0 + p * 128 + row;
                int gcol = (int)brow0 + c4 * 4;
                f32x4 v = *(const f32x4*)&Cs[row * 256 + ((c4 ^ (row & 7)) << 2)];
                if (BIAS == 1) v += bias[grow];
                if (BIAS == 2) v += *(const f32x4*)(bias + gcol);
                long off = (long)b * sCb + (long)grow * N + gcol;
                if (OMODE == 3) {
                    f32x4 rv = __builtin_nontemporal_load(
                        (const f32x4*)(resid + (long)b * sRb + (long)grow * N + gcol));
                    v += rv;
                }
                __builtin_nontemporal_store(v, (f32x4*)((float*)out0 + off));
            }
        } else {
#pragma unroll
            for (int it = 0; it < 8; ++it) {
                int elem = it * 512 + tid;
                int row = elem >> 5, c8 = elem & 31;
                int grow = (int)arow0 + p * 128 + row;
                int gcol = (int)brow0 + c8 * 8;
                int g0 = (c8 * 2) ^ (row & 7);
                int g1 = (c8 * 2 + 1) ^ (row & 7);
                f32x4 u0 = *(const f32x4*)&Cs[row * 256 + g0 * 4];
                f32x4 u1 = *(const f32x4*)&Cs[row * 256 + g1 * 4];
                float vv[8] = {u0.x, u0.y, u0.z, u0.w, u1.x, u1.y, u1.z, u1.w};
                if (BIAS == 1) {
                    float bb = bias[grow];
#pragma unroll
                    for (int q = 0; q < 8; ++q) vv[q] += bb;
                }
                if (BIAS == 2) {
#pragma unroll
                    for (int q = 0; q < 8; ++q) vv[q] += bias[gcol + q];
                }
                if (LNS) {
#pragma unroll
                    for (int q = 0; q < 8; ++q) { ls += vv[q]; lsq += vv[q] * vv[q]; }
                }
                union { u16 u[8]; u32x4 v4; } pk;
#pragma unroll
                for (int q = 0; q < 8; ++q) pk.u[q] = f2h(vv[q]);
                long off = (long)b * sCb + (long)grow * N + gcol;
                __builtin_nontemporal_store(pk.v4, (u32x4*)((u16*)out0 + off));
            }
        }
    }
    if (LNS) {
#pragma unroll
        for (int off = 32; off; off >>= 1) {
            ls += __shfl_xor(ls, off, 64);
            lsq += __shfl_xor(lsq, off, 64);
        }
        __shared__ float rsum[16];
        if (lane == 0) { rsum[wave] = ls; rsum[8 + wave] = lsq; }
        __syncthreads();
        if (tid == 0) {
            float a = 0.f, c = 0.f;
#pragma unroll
            for (int w = 0; w < 8; ++w) { a += rsum[w]; c += rsum[8 + w]; }
            atomicAdd(&lnsums[b * 2], a);
            atomicAdd(&lnsums[b * 2 + 1], c);
        }
    }
}

// ============================================================================
// SMALL kernel: 128x128, BK=64, 256 thr, 32KB LDS (4 blocks/CU). For the
// memory-bound out-proj (measured 79 vs 92 us on the big kernel).
// ============================================================================
__device__ __forceinline__ void stage_tile_sm(const u16* __restrict__ g, int ldk, u16* lds, int tid) {
#pragma unroll
    for (int it = 0; it < 4; ++it) {
        int idx = it * 256 + tid;
        int m = idx >> 3, s = idx & 7;
        int gs = s ^ (m & 7);
        gload_lds16(g + (long)m * ldk + gs * 8, lds + idx * 8);
    }
}

template<int BIAS, int OMODE>
__global__ __launch_bounds__(256, 4) void nt_gemm_sm(
    const u16* __restrict__ A, const u16* __restrict__ B,
    long sAb, long sBb, long sCb,
    int N, int Kd, int gx, int gy,
    const float* __restrict__ bias,
    void* __restrict__ out0,
    const float* __restrict__ resid, long sRb)
{
    __shared__ __align__(16) u16 smem[2 * 128 * 64];
    u16* As = smem;
    u16* Bs = smem + 128 * 64;

    const int nwg = gridDim.x;
    const int id = blockIdx.x;
    const int swz = (id & 7) * (nwg >> 3) + (id >> 3);
    const int bx = swz % gx;
    const int byz = swz / gx;
    const int by = byz % gy;
    const int b = byz / gy;

    const int tid = threadIdx.x;
    const long arow0 = (long)by * 128;
    const long brow0 = (long)bx * 128;
    const u16* Ab = A + (long)b * sAb + arow0 * Kd;
    const u16* Bb = B + (long)b * sBb + brow0 * Kd;

    const int wave = tid >> 6, lane = tid & 63;
    const int wm = (wave >> 1) * 64, wn = (wave & 1) * 64;
    const int lm = lane & 15, kg = lane >> 4;

    f32x4 acc[4][4];
#pragma unroll
    for (int i = 0; i < 4; ++i)
#pragma unroll
        for (int j = 0; j < 4; ++j) acc[i][j] = (f32x4){0.f, 0.f, 0.f, 0.f};

    for (int k0 = 0; k0 < Kd; k0 += 64) {
        stage_tile_sm(Ab + k0, Kd, As, tid);
        stage_tile_sm(Bb + k0, Kd, Bs, tid);
        __syncthreads();
#pragma unroll
        for (int ks = 0; ks < 2; ++ks) {
            half8 af[4], bf[4];
#pragma unroll
            for (int f = 0; f < 4; ++f) {
                int mr = wm + f * 16 + lm;
                int as_ = (ks * 4 + kg) ^ (mr & 7);
                af[f] = *(const half8*)(As + mr * 64 + as_ * 8);
                int nr = wn + f * 16 + lm;
                int bs_ = (ks * 4 + kg) ^ (nr & 7);
                bf[f] = *(const half8*)(Bs + nr * 64 + bs_ * 8);
            }
#pragma unroll
            for (int i = 0; i < 4; ++i)
#pragma unroll
                for (int j = 0; j < 4; ++j)
                    acc[i][j] = __builtin_amdgcn_mfma_f32_16x16x32_f16(af[i], bf[j], acc[i][j], 0, 0, 0);
        }
        __syncthreads();
    }

    float* Cs = (float*)smem;
#pragma unroll
    for (int p = 0; p < 2; ++p) {
        if (p) __syncthreads();
        if (wm == p * 64) {
#pragma unroll
            for (int i = 0; i < 4; ++i)
#pragma unroll
                for (int j = 0; j < 4; ++j)
#pragma unroll
                    for (int r = 0; r < 4; ++r) {
                        int row = i * 16 + kg * 4 + r;
                        int col = wn + j * 16 + lm;
                        Cs[row * 128 + (col ^ ((row & 7) << 2))] = acc[i][j][r];
                    }
        }
        __syncthreads();
        if (OMODE == 0 || OMODE == 3) {
#pragma unroll
            for (int rr = 0; rr < 8; ++rr) {
                int elem = rr * 256 + tid;
                int row = elem >> 5, c4 = elem & 31;
                int grow = (int)arow0 + p * 64 + row;
                int gcol = (int)brow0 + c4 * 4;
                f32x4 v = *(const f32x4*)&Cs[row * 128 + ((c4 ^ (row & 7)) << 2)];
                if (BIAS == 1) v += bias[grow];
                if (BIAS == 2) v += *(const f32x4*)(bias + gcol);
                long off = (long)b * sCb + (long)grow * N + gcol;
                if (OMODE == 3) {
                    f32x4 rv = __builtin_nontemporal_load(
                        (const f32x4*)(resid + (long)b * sRb + (long)grow * N + gcol));
                    v += rv;
                    __builtin_nontemporal_store(v, (f32x4*)((float*)out0 + off));
                } else {
                    *(f32x4*)((float*)out0 + off) = v;
                }
            }
        } else {
#pragma unroll
            for (int rr = 0; rr < 4; ++rr) {
                int elem = rr * 256 + tid;
                int row = elem >> 4, c8 = elem & 15;
                int grow = (int)arow0 + p * 64 + row;
                int gcol = (int)brow0 + c8 * 8;
                int g0 = (c8 * 2) ^ (row & 7);
                int g1 = (c8 * 2 + 1) ^ (row & 7);
                f32x4 u0 = *(const f32x4*)&Cs[row * 128 + g0 * 4];
                f32x4 u1 = *(const f32x4*)&Cs[row * 128 + g1 * 4];
                float vv[8] = {u0.x, u0.y, u0.z, u0.w, u1.x, u1.y, u1.z, u1.w};
                if (BIAS == 1) {
                    float bb = bias[grow];
#pragma unroll
                    for (int q = 0; q < 8; ++q) vv[q] += bb;
                }
                if (BIAS == 2) {
#pragma unroll
                    for (int q = 0; q < 8; ++q) vv[q] += bias[gcol + q];
                }
                union { u16 u[8]; u32x4 v4; } pk;
#pragma unroll
                for (int q = 0; q < 8; ++q) pk.u[q] = f2h(vv[q]);
                long off = (long)b * sCb + (long)grow * N + gcol;
                *(u32x4*)((u16*)out0 + off) = pk.v4;
            }
        }
    }
}

// fp32 [D][T] (per batch) -> fp16 [T][D]
__global__ __launch_bounds__(256) void transpose_h(const float* __restrict__ in,
                                                   u16* __restrict__ o16, int D, int T) {
    __shared__ float tile[64][65];
    int b = blockIdx.z;
    const float* src = in + (long)b * D * T;
    long obase = (long)b * D * T;
    int t0 = blockIdx.x * 64, d0 = blockIdx.y * 64;
    int tx = threadIdx.x & 63, ty = threadIdx.x >> 6;
#pragma unroll
    for (int i = 0; i < 64; i += 4)
        tile[ty + i][tx] = __builtin_nontemporal_load(&src[(long)(d0 + ty + i) * T + t0 + tx]);
    __syncthreads();
#pragma unroll
    for (int i = 0; i < 64; i += 4) {
        long o = obase + (long)(t0 + ty + i) * D + d0 + tx;
        o16[o] = f2h(tile[tx][ty + i]);
    }
}

// fp32 [R][C] -> fp32 [C][R]
__global__ __launch_bounds__(256) void transpose_f32(const float* __restrict__ in,
                                                     float* __restrict__ out, int R, int C) {
    __shared__ float tile[64][65];
    int c0 = blockIdx.x * 64, r0 = blockIdx.y * 64;
    int tx = threadIdx.x & 63, ty = threadIdx.x >> 6;
#pragma unroll
    for (int i = 0; i < 64; i += 4)
        tile[ty + i][tx] = in[(long)(r0 + ty + i) * C + c0 + tx];
    __syncthreads();
#pragma unroll
    for (int i = 0; i < 64; i += 4)
        out[(long)(c0 + ty + i) * R + r0 + tx] = tile[tx][ty + i];
}

__global__ __launch_bounds__(256) void conv_w(const float* __restrict__ w,
                                              u16* __restrict__ h, int n) {
    int i = blockIdx.x * 256 + threadIdx.x;
    if (i < n) h[i] = f2h(w[i]);
}

// one block per score row (2048 cols), fp32 in (nt), fp16 prob out
__global__ __launch_bounds__(256) void softmax_rows(const float* __restrict__ S, u16* __restrict__ P) {
    long row = (long)blockIdx.z * TT + blockIdx.x;
    const float* s = S + row * TT;
    u16* p = P + row * TT;
    int tid = threadIdx.x;
    f32x4 v0 = __builtin_nontemporal_load((const f32x4*)(s + tid * 8));
    f32x4 v1 = __builtin_nontemporal_load((const f32x4*)(s + tid * 8 + 4));
    float x[8] = {v0.x, v0.y, v0.z, v0.w, v1.x, v1.y, v1.z, v1.w};
    float m = x[0];
#pragma unroll
    for (int j = 1; j < 8; ++j) m = fmaxf(m, x[j]);
#pragma unroll
    for (int off = 32; off; off >>= 1) m = fmaxf(m, __shfl_xor(m, off, 64));
    __shared__ float red[8];
    int wave = tid >> 6, lane = tid & 63;
    if (lane == 0) red[wave] = m;
    __syncthreads();
    m = fmaxf(fmaxf(red[0], red[1]), fmaxf(red[2], red[3]));
    float e[8]; float sum = 0.f;
#pragma unroll
    for (int j = 0; j < 8; ++j) { e[j] = __expf(x[j] - m); sum += e[j]; }
#pragma unroll
    for (int off = 32; off; off >>= 1) sum += __shfl_xor(sum, off, 64);
    if (lane == 0) red[4 + wave] = sum;
    __syncthreads();
    sum = red[4] + red[5] + red[6] + red[7];
    float inv = 1.f / sum;
    union { u16 u[8]; u32x4 v4; } pk;
#pragma unroll
    for (int j = 0; j < 8; ++j) pk.u[j] = f2h(e[j] * inv);
    *(u32x4*)(p + tid * 8) = pk.v4;
}

__global__ void zero32(float* p) { p[threadIdx.x] = 0.f; }

__global__ __launch_bounds__(256) void ln_apply(const u16* __restrict__ TXp, const float* __restrict__ sums,
                                                const float* __restrict__ gT, const float* __restrict__ bT,
                                                u16* __restrict__ H) {
    int b = blockIdx.z;
    const float n = (float)(LL * TT);
    float mu = sums[b * 2] / n;
    float var = sums[b * 2 + 1] / n - mu * mu;
    float rstd = rsqrtf(var + LN_EPS);
    long base = (long)b * (LL * TT);
    long idx = ((long)blockIdx.x * 256 + threadIdx.x) * 8;
    u32x4 xv = *(const u32x4*)(TXp + base + idx);
    unsigned w[4] = {xv.x, xv.y, xv.z, xv.w};
    f32x4 g0 = *(const f32x4*)(gT + idx);
    f32x4 g1 = *(const f32x4*)(gT + idx + 4);
    f32x4 b0 = *(const f32x4*)(bT + idx);
    f32x4 b1 = *(const f32x4*)(bT + idx + 4);
    float g[8] = {g0.x, g0.y, g0.z, g0.w, g1.x, g1.y, g1.z, g1.w};
    float be[8] = {b0.x, b0.y, b0.z, b0.w, b1.x, b1.y, b1.z, b1.w};
    union { u16 u[8]; u32x4 v; } pk;
#pragma unroll
    for (int q = 0; q < 4; ++q) {
        float a = h2f((u16)(w[q] & 0xffff));
        float c = h2f((u16)(w[q] >> 16));
        float oa = fmaxf((a - mu) * rstd * g[q * 2] + be[q * 2], 0.f);
        float oc = fmaxf((c - mu) * rstd * g[q * 2 + 1] + be[q * 2 + 1], 0.f);
        pk.u[q * 2] = f2h(oa);
        pk.u[q * 2 + 1] = f2h(oc);
    }
    *(u32x4*)(H + base + idx) = pk.v;
}

extern "C" void kernel_launch(void* const* d_in, const int* in_sizes, int n_in,
                              void* d_out, int out_size, void* d_ws, size_t ws_size,
                              hipStream_t stream) {
    const float* input1  = (const float*)d_in[0];
    const float* input2  = (const float*)d_in[1];
    const float* theta_w = (const float*)d_in[2];
    const float* theta_b = (const float*)d_in[3];
    const float* phi_w   = (const float*)d_in[4];
    const float* phi_b   = (const float*)d_in[5];
    const float* g_w     = (const float*)d_in[6];
    const float* g_b     = (const float*)d_in[7];
    const float* ln_gamma= (const float*)d_in[8];
    const float* ln_beta = (const float*)d_in[9];
    const float* out_w   = (const float*)d_in[10];
    const float* out_b   = (const float*)d_in[11];
    float* out = (float*)d_out;

    char* ws = (char*)d_ws;
    const size_t MB = 1ull << 20;
    u16*  Xt     = (u16*)(ws + 0);          // 64MB [B][T][1024] fp16 (dead after projections)
    float* scores= (float*)(ws + 0);        // 64MB [4][T][T] fp32 (reuses Xt region)
    u16*  pmat   = (u16*)(ws + 64 * MB);    // 128MB [16][T][T] fp16
    u16*  Qf     = (u16*)(ws + 192 * MB);   // 32MB [B][T][L]
    u16*  Kf     = (u16*)(ws + 224 * MB);   // 32MB [B][T][L]
    u16*  Vt     = (u16*)(ws + 256 * MB);   // 32MB [B][L][T]
    u16*  TX     = (u16*)(ws + 288 * MB);   // 32MB [B][T][L] fp16
    u16*  H      = (u16*)(ws + 320 * MB);   // 32MB [B][T][L]
    u16*  thw    = (u16*)(ws + 352 * MB);   // 1MB each
    u16*  phw    = (u16*)(ws + 353 * MB);
    u16*  gww    = (u16*)(ws + 354 * MB);
    u16*  oww    = (u16*)(ws + 355 * MB);
    float* gammaT= (float*)(ws + 356 * MB); // 4MB [T][L]
    float* betaT = (float*)(ws + 360 * MB); // 4MB
    float* sums  = (float*)(ws + 364 * MB); // 128B

    dim3 blk(256), blk5(512);

    conv_w<<<dim3((LL * D2 + 255) / 256), blk, 0, stream>>>(theta_w, thw, LL * D2);
    conv_w<<<dim3((LL * D1 + 255) / 256), blk, 0, stream>>>(phi_w, phw, LL * D1);
    conv_w<<<dim3((LL * D1 + 255) / 256), blk, 0, stream>>>(g_w, gww, LL * D1);
    conv_w<<<dim3((D2 * LL + 255) / 256), blk, 0, stream>>>(out_w, oww, D2 * LL);
    transpose_f32<<<dim3(TT / 64, LL / 64, 1), blk, 0, stream>>>(ln_gamma, gammaT, LL, TT);
    transpose_f32<<<dim3(TT / 64, LL / 64, 1), blk, 0, stream>>>(ln_beta, betaT, LL, TT);
    zero32<<<dim3(1), dim3(32), 0, stream>>>(sums);

    // Q = theta(input2)
    transpose_h<<<dim3(TT / 64, D2 / 64, BB), blk, 0, stream>>>(input2, Xt, D2, TT);
    nt_gemm<2, 1, 0><<<dim3((LL / 256) * (TT / 256) * BB), blk5, 0, stream>>>(
        Xt, thw, (long)TT * D2, 0, (long)TT * LL, LL, D2, LL / 256, TT / 256,
        theta_b, Qf, nullptr, 0, nullptr);

    // K = phi(input1), V^T = g(input1)
    transpose_h<<<dim3(TT / 64, D1 / 64, BB), blk, 0, stream>>>(input1, Xt, D1, TT);
    nt_gemm<2, 1, 0><<<dim3((LL / 256) * (TT / 256) * BB), blk5, 0, stream>>>(
        Xt, phw, (long)TT * D1, 0, (long)TT * LL, LL, D1, LL / 256, TT / 256,
        phi_b, Kf, nullptr, 0, nullptr);
    nt_gemm<1, 1, 0><<<dim3((TT / 256) * (LL / 256) * BB), blk5, 0, stream>>>(
        gww, Xt, 0, (long)TT * D1, (long)LL * TT, TT, D1, TT / 256, LL / 256,
        g_b, Vt, nullptr, 0, nullptr);

    // attention scores+softmax, 4 batches per chunk (scores reuse Xt region)
    for (int c = 0; c < 4; ++c) {
        long qoff = (long)c * 4 * TT * LL;
        nt_gemm<0, 0, 0><<<dim3((TT / 256) * (TT / 256) * 4), blk5, 0, stream>>>(
            Qf + qoff, Kf + qoff, (long)TT * LL, (long)TT * LL, (long)TT * TT,
            TT, LL, TT / 256, TT / 256, nullptr, scores, nullptr, 0, nullptr);
        softmax_rows<<<dim3(TT, 1, 4), blk, 0, stream>>>(scores, pmat + (long)c * 4 * TT * TT);
    }
    // PV: one full-GPU dispatch over all 16 batches, LayerNorm sums fused
    nt_gemm<0, 1, 1><<<dim3((LL / 256) * (TT / 256) * BB), blk5, 0, stream>>>(
        pmat, Vt, (long)TT * TT, (long)LL * TT, (long)TT * LL,
        LL, TT, LL / 256, TT / 256, nullptr, TX, nullptr, 0, sums);

    ln_apply<<<dim3(512, 1, BB), blk, 0, stream>>>(TX, sums, gammaT, betaT, H);

    // out = out_w * h + out_b + input2  (small kernel: measured 79 vs 92 us)
    nt_gemm_sm<1, 3><<<dim3((TT / 128) * (D2 / 128) * BB), blk, 0, stream>>>(
        oww, H, 0, (long)TT * LL, (long)D2 * TT, TT, LL, TT / 128, D2 / 128,
        out_b, out, input2, (long)D2 * TT);
}

// Round 12
// 562.881 us; speedup vs baseline: 1.2916x; 1.0062x over previous
//
#include <hip/hip_runtime.h>
#include <hip/hip_bf16.h>

#define BB 16
#define D1 1024
#define D2 1024
#define LL 512
#define TT 2048
#define LN_EPS 1e-5f

typedef unsigned short u16;
typedef __attribute__((ext_vector_type(8))) _Float16 half8;
typedef __attribute__((ext_vector_type(4))) float f32x4;
typedef __attribute__((ext_vector_type(4))) unsigned int u32x4;

__device__ __forceinline__ u16 f2h(float v) {
    _Float16 h = (_Float16)v;
    return *(u16*)&h;
}
__device__ __forceinline__ float h2f(u16 u) {
    return (float)(*(const _Float16*)&u);
}

__device__ __forceinline__ void gload_lds16(const void* g, void* l) {
    __builtin_amdgcn_global_load_lds((const __attribute__((address_space(1))) void*)g,
                                     (__attribute__((address_space(3))) void*)l, 16, 0, 0);
}

#define MEMFENCE asm volatile("" ::: "memory")
__device__ __forceinline__ void block_barrier() {
    MEMFENCE; __builtin_amdgcn_s_barrier(); MEMFENCE;
}

// ============================================================================
// BIG kernel: 256x256 tile, BK=64, 512 threads (8 waves, 2Mx4N),
// double-buffered LDS, counted vmcnt(8). Projections + QK^T + PV.
// LNS=1 (with OMODE=1): accumulate LayerNorm sum/sumsq of C per batch.
// NOTE: OMODE 0/1 outputs are REUSED intermediates -> plain (cached) stores;
// only OMODE=3 (final out + resid) uses nt.
// ============================================================================
template<int BIAS, int OMODE, int LNS>
__global__ __launch_bounds__(512, 2) void nt_gemm(
    const u16* __restrict__ A, const u16* __restrict__ B,
    long sAb, long sBb, long sCb,
    int N, int Kd, int gx, int gy,
    const float* __restrict__ bias,
    void* __restrict__ out0,
    const float* __restrict__ resid, long sRb,
    float* __restrict__ lnsums)
{
    __shared__ __align__(16) u16 smem[65536];

    const int nwg = gridDim.x;
    const int id = blockIdx.x;
    const int swz = (id & 7) * (nwg >> 3) + (id >> 3);
    const int bx = swz % gx;
    const int byz = swz / gx;
    const int by = byz % gy;
    const int b = byz / gy;

    const int tid = threadIdx.x;
    const long arow0 = (long)by * 256;
    const long brow0 = (long)bx * 256;
    const u16* Ab = A + (long)b * sAb + arow0 * Kd;
    const u16* Bb = B + (long)b * sBb + brow0 * Kd;

    const int wave = tid >> 6, lane = tid & 63;
    const int wm = (wave >> 2) * 128, wn = (wave & 3) * 64;
    const int lm = lane & 15, kg = lane >> 4;

    const int m0 = tid >> 3, s0 = tid & 7;
    const int nt = Kd >> 6;

    auto STAGE = [&](int buf, long k0) {
        u16* Ad = smem + buf * 32768;
        u16* Bd = smem + buf * 32768 + 16384;
#pragma unroll
        for (int call = 0; call < 4; ++call) {
            int m = call * 64 + m0;
            int gs = s0 ^ (m & 7);
            gload_lds16(Ab + k0 + (long)m * Kd + gs * 8, Ad + (call * 512 + tid) * 8);
        }
#pragma unroll
        for (int call = 0; call < 4; ++call) {
            int m = call * 64 + m0;
            int gs = s0 ^ (m & 7);
            gload_lds16(Bb + k0 + (long)m * Kd + gs * 8, Bd + (call * 512 + tid) * 8);
        }
    };

    f32x4 acc[8][4];
#pragma unroll
    for (int i = 0; i < 8; ++i)
#pragma unroll
        for (int j = 0; j < 4; ++j) acc[i][j] = (f32x4){0.f, 0.f, 0.f, 0.f};

    STAGE(0, 0);
    if (nt > 1) STAGE(1, 64);

    for (int t = 0; t < nt; ++t) {
        const int cur = t & 1;
        if (t + 1 < nt) { asm volatile("s_waitcnt vmcnt(8)" ::: "memory"); }
        else           { asm volatile("s_waitcnt vmcnt(0)" ::: "memory"); }
        block_barrier();

        const u16* Ac = smem + cur * 32768;
        const u16* Bc = smem + cur * 32768 + 16384;

        half8 bf[4][2];
#pragma unroll
        for (int f = 0; f < 4; ++f)
#pragma unroll
            for (int kf = 0; kf < 2; ++kf) {
                int nr = wn + f * 16 + lm;
                int ss = (kf * 4 + kg) ^ (nr & 7);
                bf[f][kf] = *(const half8*)(Bc + nr * 64 + ss * 8);
            }
#pragma unroll
        for (int mh = 0; mh < 2; ++mh) {
            half8 af[4][2];
#pragma unroll
            for (int f = 0; f < 4; ++f)
#pragma unroll
                for (int kf = 0; kf < 2; ++kf) {
                    int mr = wm + mh * 64 + f * 16 + lm;
                    int ss = (kf * 4 + kg) ^ (mr & 7);
                    af[f][kf] = *(const half8*)(Ac + mr * 64 + ss * 8);
                }
            __builtin_amdgcn_s_setprio(1);
#pragma unroll
            for (int f = 0; f < 4; ++f)
#pragma unroll
                for (int j = 0; j < 4; ++j)
#pragma unroll
                    for (int kf = 0; kf < 2; ++kf)
                        acc[mh * 4 + f][j] = __builtin_amdgcn_mfma_f32_16x16x32_f16(
                            af[f][kf], bf[j][kf], acc[mh * 4 + f][j], 0, 0, 0);
            __builtin_amdgcn_s_setprio(0);
        }
        block_barrier();
        if (t + 2 < nt) STAGE(cur, (long)(t + 2) * 64);
    }

    // ---- epilogue: LDS-staged (swizzled), coalesced stores; two 128-row passes ----
    float ls = 0.f, lsq = 0.f;
    float* Cs = (float*)smem;   // 128 x 256 fp32 = 128 KB
#pragma unroll
    for (int p = 0; p < 2; ++p) {
        __syncthreads();
        if (wm == p * 128) {
#pragma unroll
            for (int i = 0; i < 8; ++i)
#pragma unroll
                for (int j = 0; j < 4; ++j)
#pragma unroll
                    for (int r = 0; r < 4; ++r) {
                        int row = i * 16 + kg * 4 + r;
                        int col = wn + j * 16 + lm;
                        Cs[row * 256 + (col ^ ((row & 7) << 2))] = acc[i][j][r];
                    }
        }
        __syncthreads();
        if (OMODE == 0 || OMODE == 3) {
#pragma unroll
            for (int it = 0; it < 16; ++it) {
                int elem = it * 512 + tid;
                int row = elem >> 6, c4 = elem & 63;
                int grow = (int)arow0 + p * 128 + row;
                int gcol = (int)brow0 + c4 * 4;
                f32x4 v = *(const f32x4*)&Cs[row * 256 + ((c4 ^ (row & 7)) << 2)];
                if (BIAS == 1) v += bias[grow];
                if (BIAS == 2) v += *(const f32x4*)(bias + gcol);
                long off = (long)b * sCb + (long)grow * N + gcol;
                if (OMODE == 3) {
                    f32x4 rv = __builtin_nontemporal_load(
                        (const f32x4*)(resid + (long)b * sRb + (long)grow * N + gcol));
                    v += rv;
                    __builtin_nontemporal_store(v, (f32x4*)((float*)out0 + off));
                } else {
                    *(f32x4*)((float*)out0 + off) = v;   // scores: L3-resident, reused
                }
            }
        } else {
#pragma unroll
            for (int it = 0; it < 8; ++it) {
                int elem = it * 512 + tid;
                int row = elem >> 5, c8 = elem & 31;
                int grow = (int)arow0 + p * 128 + row;
                int gcol = (int)brow0 + c8 * 8;
                int g0 = (c8 * 2) ^ (row & 7);
                int g1 = (c8 * 2 + 1) ^ (row & 7);
                f32x4 u0 = *(const f32x4*)&Cs[row * 256 + g0 * 4];
                f32x4 u1 = *(const f32x4*)&Cs[row * 256 + g1 * 4];
                float vv[8] = {u0.x, u0.y, u0.z, u0.w, u1.x, u1.y, u1.z, u1.w};
                if (BIAS == 1) {
                    float bb = bias[grow];
#pragma unroll
                    for (int q = 0; q < 8; ++q) vv[q] += bb;
                }
                if (BIAS == 2) {
#pragma unroll
                    for (int q = 0; q < 8; ++q) vv[q] += bias[gcol + q];
                }
                if (LNS) {
#pragma unroll
                    for (int q = 0; q < 8; ++q) { ls += vv[q]; lsq += vv[q] * vv[q]; }
                }
                union { u16 u[8]; u32x4 v4; } pk;
#pragma unroll
                for (int q = 0; q < 8; ++q) pk.u[q] = f2h(vv[q]);
                long off = (long)b * sCb + (long)grow * N + gcol;
                *(u32x4*)((u16*)out0 + off) = pk.v4;   // reused intermediate: cached store
            }
        }
    }
    if (LNS) {
#pragma unroll
        for (int off = 32; off; off >>= 1) {
            ls += __shfl_xor(ls, off, 64);
            lsq += __shfl_xor(lsq, off, 64);
        }
        __shared__ float rsum[16];
        if (lane == 0) { rsum[wave] = ls; rsum[8 + wave] = lsq; }
        __syncthreads();
        if (tid == 0) {
            float a = 0.f, c = 0.f;
#pragma unroll
            for (int w = 0; w < 8; ++w) { a += rsum[w]; c += rsum[8 + w]; }
            atomicAdd(&lnsums[b * 2], a);
            atomicAdd(&lnsums[b * 2 + 1], c);
        }
    }
}

// ============================================================================
// SMALL kernel: 128x128, BK=64, 256 thr, 32KB LDS (4 blocks/CU). For the
// memory-bound out-proj (measured 79 vs 92 us on the big kernel).
// ============================================================================
__device__ __forceinline__ void stage_tile_sm(const u16* __restrict__ g, int ldk, u16* lds, int tid) {
#pragma unroll
    for (int it = 0; it < 4; ++it) {
        int idx = it * 256 + tid;
        int m = idx >> 3, s = idx & 7;
        int gs = s ^ (m & 7);
        gload_lds16(g + (long)m * ldk + gs * 8, lds + idx * 8);
    }
}

template<int BIAS, int OMODE>
__global__ __launch_bounds__(256, 4) void nt_gemm_sm(
    const u16* __restrict__ A, const u16* __restrict__ B,
    long sAb, long sBb, long sCb,
    int N, int Kd, int gx, int gy,
    const float* __restrict__ bias,
    void* __restrict__ out0,
    const float* __restrict__ resid, long sRb)
{
    __shared__ __align__(16) u16 smem[2 * 128 * 64];
    u16* As = smem;
    u16* Bs = smem + 128 * 64;

    const int nwg = gridDim.x;
    const int id = blockIdx.x;
    const int swz = (id & 7) * (nwg >> 3) + (id >> 3);
    const int bx = swz % gx;
    const int byz = swz / gx;
    const int by = byz % gy;
    const int b = byz / gy;

    const int tid = threadIdx.x;
    const long arow0 = (long)by * 128;
    const long brow0 = (long)bx * 128;
    const u16* Ab = A + (long)b * sAb + arow0 * Kd;
    const u16* Bb = B + (long)b * sBb + brow0 * Kd;

    const int wave = tid >> 6, lane = tid & 63;
    const int wm = (wave >> 1) * 64, wn = (wave & 1) * 64;
    const int lm = lane & 15, kg = lane >> 4;

    f32x4 acc[4][4];
#pragma unroll
    for (int i = 0; i < 4; ++i)
#pragma unroll
        for (int j = 0; j < 4; ++j) acc[i][j] = (f32x4){0.f, 0.f, 0.f, 0.f};

    for (int k0 = 0; k0 < Kd; k0 += 64) {
        stage_tile_sm(Ab + k0, Kd, As, tid);
        stage_tile_sm(Bb + k0, Kd, Bs, tid);
        __syncthreads();
#pragma unroll
        for (int ks = 0; ks < 2; ++ks) {
            half8 af[4], bf[4];
#pragma unroll
            for (int f = 0; f < 4; ++f) {
                int mr = wm + f * 16 + lm;
                int as_ = (ks * 4 + kg) ^ (mr & 7);
                af[f] = *(const half8*)(As + mr * 64 + as_ * 8);
                int nr = wn + f * 16 + lm;
                int bs_ = (ks * 4 + kg) ^ (nr & 7);
                bf[f] = *(const half8*)(Bs + nr * 64 + bs_ * 8);
            }
#pragma unroll
            for (int i = 0; i < 4; ++i)
#pragma unroll
                for (int j = 0; j < 4; ++j)
                    acc[i][j] = __builtin_amdgcn_mfma_f32_16x16x32_f16(af[i], bf[j], acc[i][j], 0, 0, 0);
        }
        __syncthreads();
    }

    float* Cs = (float*)smem;
#pragma unroll
    for (int p = 0; p < 2; ++p) {
        if (p) __syncthreads();
        if (wm == p * 64) {
#pragma unroll
            for (int i = 0; i < 4; ++i)
#pragma unroll
                for (int j = 0; j < 4; ++j)
#pragma unroll
                    for (int r = 0; r < 4; ++r) {
                        int row = i * 16 + kg * 4 + r;
                        int col = wn + j * 16 + lm;
                        Cs[row * 128 + (col ^ ((row & 7) << 2))] = acc[i][j][r];
                    }
        }
        __syncthreads();
        if (OMODE == 0 || OMODE == 3) {
#pragma unroll
            for (int rr = 0; rr < 8; ++rr) {
                int elem = rr * 256 + tid;
                int row = elem >> 5, c4 = elem & 31;
                int grow = (int)arow0 + p * 64 + row;
                int gcol = (int)brow0 + c4 * 4;
                f32x4 v = *(const f32x4*)&Cs[row * 128 + ((c4 ^ (row & 7)) << 2)];
                if (BIAS == 1) v += bias[grow];
                if (BIAS == 2) v += *(const f32x4*)(bias + gcol);
                long off = (long)b * sCb + (long)grow * N + gcol;
                if (OMODE == 3) {
                    f32x4 rv = __builtin_nontemporal_load(
                        (const f32x4*)(resid + (long)b * sRb + (long)grow * N + gcol));
                    v += rv;
                    __builtin_nontemporal_store(v, (f32x4*)((float*)out0 + off));
                } else {
                    *(f32x4*)((float*)out0 + off) = v;
                }
            }
        } else {
#pragma unroll
            for (int rr = 0; rr < 4; ++rr) {
                int elem = rr * 256 + tid;
                int row = elem >> 4, c8 = elem & 15;
                int grow = (int)arow0 + p * 64 + row;
                int gcol = (int)brow0 + c8 * 8;
                int g0 = (c8 * 2) ^ (row & 7);
                int g1 = (c8 * 2 + 1) ^ (row & 7);
                f32x4 u0 = *(const f32x4*)&Cs[row * 128 + g0 * 4];
                f32x4 u1 = *(const f32x4*)&Cs[row * 128 + g1 * 4];
                float vv[8] = {u0.x, u0.y, u0.z, u0.w, u1.x, u1.y, u1.z, u1.w};
                if (BIAS == 1) {
                    float bb = bias[grow];
#pragma unroll
                    for (int q = 0; q < 8; ++q) vv[q] += bb;
                }
                if (BIAS == 2) {
#pragma unroll
                    for (int q = 0; q < 8; ++q) vv[q] += bias[gcol + q];
                }
                union { u16 u[8]; u32x4 v4; } pk;
#pragma unroll
                for (int q = 0; q < 8; ++q) pk.u[q] = f2h(vv[q]);
                long off = (long)b * sCb + (long)grow * N + gcol;
                *(u32x4*)((u16*)out0 + off) = pk.v4;
            }
        }
    }
}

// fp32 [D][T] (per batch) -> fp16 [T][D]
__global__ __launch_bounds__(256) void transpose_h(const float* __restrict__ in,
                                                   u16* __restrict__ o16, int D, int T) {
    __shared__ float tile[64][65];
    int b = blockIdx.z;
    const float* src = in + (long)b * D * T;
    long obase = (long)b * D * T;
    int t0 = blockIdx.x * 64, d0 = blockIdx.y * 64;
    int tx = threadIdx.x & 63, ty = threadIdx.x >> 6;
#pragma unroll
    for (int i = 0; i < 64; i += 4)
        tile[ty + i][tx] = __builtin_nontemporal_load(&src[(long)(d0 + ty + i) * T + t0 + tx]);
    __syncthreads();
#pragma unroll
    for (int i = 0; i < 64; i += 4) {
        long o = obase + (long)(t0 + ty + i) * D + d0 + tx;
        o16[o] = f2h(tile[tx][ty + i]);
    }
}

// fp32 [R][C] -> fp32 [C][R]
__global__ __launch_bounds__(256) void transpose_f32(const float* __restrict__ in,
                                                     float* __restrict__ out, int R, int C) {
    __shared__ float tile[64][65];
    int c0 = blockIdx.x * 64, r0 = blockIdx.y * 64;
    int tx = threadIdx.x & 63, ty = threadIdx.x >> 6;
#pragma unroll
    for (int i = 0; i < 64; i += 4)
        tile[ty + i][tx] = in[(long)(r0 + ty + i) * C + c0 + tx];
    __syncthreads();
#pragma unroll
    for (int i = 0; i < 64; i += 4)
        out[(long)(c0 + ty + i) * R + r0 + tx] = tile[tx][ty + i];
}

__global__ __launch_bounds__(256) void conv_w(const float* __restrict__ w,
                                              u16* __restrict__ h, int n) {
    int i = blockIdx.x * 256 + threadIdx.x;
    if (i < n) h[i] = f2h(w[i]);
}

// one block per score row (2048 cols), fp32 in (L3-resident, plain loads),
// fp16 prob out
__global__ __launch_bounds__(256) void softmax_rows(const float* __restrict__ S, u16* __restrict__ P) {
    long row = (long)blockIdx.z * TT + blockIdx.x;
    const float* s = S + row * TT;
    u16* p = P + row * TT;
    int tid = threadIdx.x;
    f32x4 v0 = *(const f32x4*)(s + tid * 8);
    f32x4 v1 = *(const f32x4*)(s + tid * 8 + 4);
    float x[8] = {v0.x, v0.y, v0.z, v0.w, v1.x, v1.y, v1.z, v1.w};
    float m = x[0];
#pragma unroll
    for (int j = 1; j < 8; ++j) m = fmaxf(m, x[j]);
#pragma unroll
    for (int off = 32; off; off >>= 1) m = fmaxf(m, __shfl_xor(m, off, 64));
    __shared__ float red[8];
    int wave = tid >> 6, lane = tid & 63;
    if (lane == 0) red[wave] = m;
    __syncthreads();
    m = fmaxf(fmaxf(red[0], red[1]), fmaxf(red[2], red[3]));
    float e[8]; float sum = 0.f;
#pragma unroll
    for (int j = 0; j < 8; ++j) { e[j] = __expf(x[j] - m); sum += e[j]; }
#pragma unroll
    for (int off = 32; off; off >>= 1) sum += __shfl_xor(sum, off, 64);
    if (lane == 0) red[4 + wave] = sum;
    __syncthreads();
    sum = red[4] + red[5] + red[6] + red[7];
    float inv = 1.f / sum;
    union { u16 u[8]; u32x4 v4; } pk;
#pragma unroll
    for (int j = 0; j < 8; ++j) pk.u[j] = f2h(e[j] * inv);
    *(u32x4*)(p + tid * 8) = pk.v4;
}

__global__ void zero32(float* p) { p[threadIdx.x] = 0.f; }

__global__ __launch_bounds__(256) void ln_apply(const u16* __restrict__ TXp, const float* __restrict__ sums,
                                                const float* __restrict__ gT, const float* __restrict__ bT,
                                                u16* __restrict__ H) {
    int b = blockIdx.z;
    const float n = (float)(LL * TT);
    float mu = sums[b * 2] / n;
    float var = sums[b * 2 + 1] / n - mu * mu;
    float rstd = rsqrtf(var + LN_EPS);
    long base = (long)b * (LL * TT);
    long idx = ((long)blockIdx.x * 256 + threadIdx.x) * 8;
    u32x4 xv = *(const u32x4*)(TXp + base + idx);
    unsigned w[4] = {xv.x, xv.y, xv.z, xv.w};
    f32x4 g0 = *(const f32x4*)(gT + idx);
    f32x4 g1 = *(const f32x4*)(gT + idx + 4);
    f32x4 b0 = *(const f32x4*)(bT + idx);
    f32x4 b1 = *(const f32x4*)(bT + idx + 4);
    float g[8] = {g0.x, g0.y, g0.z, g0.w, g1.x, g1.y, g1.z, g1.w};
    float be[8] = {b0.x, b0.y, b0.z, b0.w, b1.x, b1.y, b1.z, b1.w};
    union { u16 u[8]; u32x4 v; } pk;
#pragma unroll
    for (int q = 0; q < 4; ++q) {
        float a = h2f((u16)(w[q] & 0xffff));
        float c = h2f((u16)(w[q] >> 16));
        float oa = fmaxf((a - mu) * rstd * g[q * 2] + be[q * 2], 0.f);
        float oc = fmaxf((c - mu) * rstd * g[q * 2 + 1] + be[q * 2 + 1], 0.f);
        pk.u[q * 2] = f2h(oa);
        pk.u[q * 2 + 1] = f2h(oc);
    }
    *(u32x4*)(H + base + idx) = pk.v;
}

extern "C" void kernel_launch(void* const* d_in, const int* in_sizes, int n_in,
                              void* d_out, int out_size, void* d_ws, size_t ws_size,
                              hipStream_t stream) {
    const float* input1  = (const float*)d_in[0];
    const float* input2  = (const float*)d_in[1];
    const float* theta_w = (const float*)d_in[2];
    const float* theta_b = (const float*)d_in[3];
    const float* phi_w   = (const float*)d_in[4];
    const float* phi_b   = (const float*)d_in[5];
    const float* g_w     = (const float*)d_in[6];
    const float* g_b     = (const float*)d_in[7];
    const float* ln_gamma= (const float*)d_in[8];
    const float* ln_beta = (const float*)d_in[9];
    const float* out_w   = (const float*)d_in[10];
    const float* out_b   = (const float*)d_in[11];
    float* out = (float*)d_out;

    char* ws = (char*)d_ws;
    const size_t MB = 1ull << 20;
    u16*  Xt     = (u16*)(ws + 0);          // 64MB [B][T][1024] fp16 (dead after projections)
    float* scores= (float*)(ws + 0);        // 64MB [4][T][T] fp32 (reuses Xt region, L3-resident)
    u16*  pmat   = (u16*)(ws + 64 * MB);    // 128MB [16][T][T] fp16
    u16*  Qf     = (u16*)(ws + 192 * MB);   // 32MB [B][T][L]
    u16*  Kf     = (u16*)(ws + 224 * MB);   // 32MB [B][T][L]
    u16*  Vt     = (u16*)(ws + 256 * MB);   // 32MB [B][L][T]
    u16*  TX     = (u16*)(ws + 288 * MB);   // 32MB [B][T][L] fp16
    u16*  H      = (u16*)(ws + 320 * MB);   // 32MB [B][T][L]
    u16*  thw    = (u16*)(ws + 352 * MB);   // 1MB each
    u16*  phw    = (u16*)(ws + 353 * MB);
    u16*  gww    = (u16*)(ws + 354 * MB);
    u16*  oww    = (u16*)(ws + 355 * MB);
    float* gammaT= (float*)(ws + 356 * MB); // 4MB [T][L]
    float* betaT = (float*)(ws + 360 * MB); // 4MB
    float* sums  = (float*)(ws + 364 * MB); // 128B

    dim3 blk(256), blk5(512);

    conv_w<<<dim3((LL * D2 + 255) / 256), blk, 0, stream>>>(theta_w, thw, LL * D2);
    conv_w<<<dim3((LL * D1 + 255) / 256), blk, 0, stream>>>(phi_w, phw, LL * D1);
    conv_w<<<dim3((LL * D1 + 255) / 256), blk, 0, stream>>>(g_w, gww, LL * D1);
    conv_w<<<dim3((D2 * LL + 255) / 256), blk, 0, stream>>>(out_w, oww, D2 * LL);
    transpose_f32<<<dim3(TT / 64, LL / 64, 1), blk, 0, stream>>>(ln_gamma, gammaT, LL, TT);
    transpose_f32<<<dim3(TT / 64, LL / 64, 1), blk, 0, stream>>>(ln_beta, betaT, LL, TT);
    zero32<<<dim3(1), dim3(32), 0, stream>>>(sums);

    // Q = theta(input2)
    transpose_h<<<dim3(TT / 64, D2 / 64, BB), blk, 0, stream>>>(input2, Xt, D2, TT);
    nt_gemm<2, 1, 0><<<dim3((LL / 256) * (TT / 256) * BB), blk5, 0, stream>>>(
        Xt, thw, (long)TT * D2, 0, (long)TT * LL, LL, D2, LL / 256, TT / 256,
        theta_b, Qf, nullptr, 0, nullptr);

    // K = phi(input1), V^T = g(input1)
    transpose_h<<<dim3(TT / 64, D1 / 64, BB), blk, 0, stream>>>(input1, Xt, D1, TT);
    nt_gemm<2, 1, 0><<<dim3((LL / 256) * (TT / 256) * BB), blk5, 0, stream>>>(
        Xt, phw, (long)TT * D1, 0, (long)TT * LL, LL, D1, LL / 256, TT / 256,
        phi_b, Kf, nullptr, 0, nullptr);
    nt_gemm<1, 1, 0><<<dim3((TT / 256) * (LL / 256) * BB), blk5, 0, stream>>>(
        gww, Xt, 0, (long)TT * D1, (long)LL * TT, TT, D1, TT / 256, LL / 256,
        g_b, Vt, nullptr, 0, nullptr);

    // attention scores+softmax, 4 batches per chunk (scores reuse Xt region)
    for (int c = 0; c < 4; ++c) {
        long qoff = (long)c * 4 * TT * LL;
        nt_gemm<0, 0, 0><<<dim3((TT / 256) * (TT / 256) * 4), blk5, 0, stream>>>(
            Qf + qoff, Kf + qoff, (long)TT * LL, (long)TT * LL, (long)TT * TT,
            TT, LL, TT / 256, TT / 256, nullptr, scores, nullptr, 0, nullptr);
        softmax_rows<<<dim3(TT, 1, 4), blk, 0, stream>>>(scores, pmat + (long)c * 4 * TT * TT);
    }
    // PV: one full-GPU dispatch over all 16 batches, LayerNorm sums fused
    nt_gemm<0, 1, 1><<<dim3((LL / 256) * (TT / 256) * BB), blk5, 0, stream>>>(
        pmat, Vt, (long)TT * TT, (long)LL * TT, (long)TT * LL,
        LL, TT, LL / 256, TT / 256, nullptr, TX, nullptr, 0, sums);

    ln_apply<<<dim3(512, 1, BB), blk, 0, stream>>>(TX, sums, gammaT, betaT, H);

    // out = out_w * h + out_b + input2  (small kernel: measured 79 vs 92 us)
    nt_gemm_sm<1, 3><<<dim3((TT / 128) * (D2 / 128) * BB), blk, 0, stream>>>(
        oww, H, 0, (long)TT * LL, (long)D2 * TT, TT, LL, TT / 128, D2 / 128,
        out_b, out, input2, (long)D2 * TT);
}